// Round 12
// baseline (237.070 us; speedup 1.0000x reference)
//
#include <hip/hip_runtime.h>
#include <hip/hip_bf16.h>
#include <math.h>

#define N_TOK 4096
#define HID   1024
#define FFN   2048
#define NEXP  8
#define WROW  (NEXP*FFN)    /* 16384: row stride of w1 */
#define NSLOT (N_TOK*2)     /* 8192 (token,k) slots    */
#define NCHUNK (NSLOT/64)   /* 128 ballot chunks       */

typedef __attribute__((ext_vector_type(4))) float f32x4;
typedef __attribute__((ext_vector_type(8))) short short8;

__device__ inline unsigned short f2bf(float f) {
  union { float f; unsigned u; } v; v.f = f;
  unsigned r = v.u + 0x7fffu + ((v.u >> 16) & 1u);   // RNE to bf16
  return (unsigned short)(r >> 16);
}
__device__ __forceinline__ float bf2f(unsigned short u) {
  union { unsigned u; float f; } v; v.u = ((unsigned)u) << 16; return v.f;
}

// tanh-form GELU: |err| vs exact erf-gelu <= ~3e-3, sub-ulp of bf16 storage of h1.
__device__ __forceinline__ float gelu_f(float v) {
  const float u = 1.5957691216057308f * v + 0.07135481627f * (v * v * v);
  return v / (1.f + __expf(-u));
}

__device__ __forceinline__ void gload16(const void* g, void* l) {
  __builtin_amdgcn_global_load_lds((const __attribute__((address_space(1))) void*)g,
                                   (__attribute__((address_space(3))) void*)l, 16, 0, 0);
}

// T2 chunk-swizzle (r7: conflicts 4.39M->0). T5 setprio (r10: +4us).
// r12: depth-3 prefetch (4 LDS buffers, vmcnt(8) steady-state) — depth-2 left
// ~400cyc HBM-latency stall per K-step (MfmaUtil 20% = 78/400 match, m126 900cyc).

// ---------------- prep: router (blocks 0..1023) + both tconvs (blocks 1024..9215) ----------------
__global__ __launch_bounds__(256) void prep_kernel(
    const float* __restrict__ x, const float* __restrict__ rw,
    int* __restrict__ eidx, float* __restrict__ probs, unsigned short* __restrict__ xb,
    const float* __restrict__ w1, const float* __restrict__ w2,
    unsigned short* __restrict__ w1t, unsigned short* __restrict__ w2t) {
  __shared__ float rwT[NEXP][HID];   // 32 KB (router)
  __shared__ float tile[64][65];     // 16.6 KB (tconv)
  const int t = threadIdx.x;

  if (blockIdx.x < N_TOK / 4) {
    // ---- router: 4 tokens/block, rw^T in LDS, no atomics ----
    #pragma unroll
    for (int it = 0; it < 8; ++it) {
      const int flat = t * 4 + it * 1024;
      const f32x4 v = *(const f32x4*)&rw[flat];
      #pragma unroll
      for (int j = 0; j < 4; ++j) rwT[(flat + j) & 7][(flat + j) >> 3] = v[j];
    }
    __syncthreads();

    const int w = t >> 6, l = t & 63;
    const int n = blockIdx.x * 4 + w;
    const float* xr = x + (size_t)n * HID;
    float acc[NEXP];
    #pragma unroll
    for (int e = 0; e < NEXP; ++e) acc[e] = 0.f;

    #pragma unroll
    for (int j = 0; j < 4; ++j) {
      const int i = l * 4 + j * 256;
      const f32x4 xv = *(const f32x4*)&xr[i];
      if (xb) {
        ushort4 o;
        o.x = f2bf(xv[0]); o.y = f2bf(xv[1]); o.z = f2bf(xv[2]); o.w = f2bf(xv[3]);
        *(ushort4*)&xb[(size_t)n * HID + i] = o;
      }
      #pragma unroll
      for (int e = 0; e < NEXP; ++e) {
        const f32x4 wv = *(const f32x4*)&rwT[e][i];
        acc[e] += xv[0] * wv[0] + xv[1] * wv[1] + xv[2] * wv[2] + xv[3] * wv[3];
      }
    }
    #pragma unroll
    for (int e = 0; e < NEXP; ++e) {
      float s = acc[e];
      #pragma unroll
      for (int off = 32; off; off >>= 1) s += __shfl_xor(s, off);
      acc[e] = s;
    }
    if (l == 0) {
      float m = acc[0];
      #pragma unroll
      for (int e = 1; e < NEXP; ++e) m = fmaxf(m, acc[e]);
      float p[NEXP]; float den = 0.f;
      #pragma unroll
      for (int e = 0; e < NEXP; ++e) { p[e] = expf(acc[e] - m); den += p[e]; }
      const float inv = 1.f / den;
      int e1 = 0; float b1 = -1.f;
      #pragma unroll
      for (int e = 0; e < NEXP; ++e) if (p[e] > b1) { b1 = p[e]; e1 = e; }
      int e2 = 0; float b2 = -1.f;
      #pragma unroll
      for (int e = 0; e < NEXP; ++e) if (e != e1 && p[e] > b2) { b2 = p[e]; e2 = e; }
      eidx[n * 2 + 0] = e1; eidx[n * 2 + 1] = e2;
      probs[n * 2 + 0] = b1 * inv; probs[n * 2 + 1] = b2 * inv;
    }
    return;
  }

  // ---- tconv: in [R][C] fp32 -> out bf16 [r/RB][C][r%RB] ----
  int b = blockIdx.x - N_TOK / 4;
  const float* in; unsigned short* out; int C, RB, r0, c0;
  if (b < 4096) {                 // w1 [1024][16384] -> w1t [16384][1024]
    in = w1; out = w1t; C = WROW; RB = HID;
    c0 = (b & 255) * 64; r0 = (b >> 8) * 64;
  } else {                        // w2 [16384][1024] -> w2t [8][1024][2048]
    b -= 4096;
    in = w2; out = w2t; C = HID; RB = FFN;
    c0 = (b & 15) * 64; r0 = (b >> 4) * 64;
  }
  const int tr = t >> 4;
  const int tc4 = (t & 15) * 4;
  #pragma unroll
  for (int i = 0; i < 4; ++i) {
    const int r = tr + i * 16;
    const f32x4 v = *(const f32x4*)&in[(size_t)(r0 + r) * C + c0 + tc4];
    tile[r][tc4 + 0] = v[0]; tile[r][tc4 + 1] = v[1];
    tile[r][tc4 + 2] = v[2]; tile[r][tc4 + 3] = v[3];
  }
  __syncthreads();
  const int eb  = r0 / RB;
  const int rm0 = r0 % RB;
  #pragma unroll
  for (int i = 0; i < 4; ++i) {
    const int c = tr + i * 16;
    ushort4 o;
    o.x = f2bf(tile[tc4 + 0][c]); o.y = f2bf(tile[tc4 + 1][c]);
    o.z = f2bf(tile[tc4 + 2][c]); o.w = f2bf(tile[tc4 + 3][c]);
    const size_t oidx = (size_t)eb * C * RB + (size_t)(c0 + c) * RB + rm0 + tc4;
    *(ushort4*)&out[oidx] = o;
  }
}

// ---------------- dispatch: single block; ballot histogram + scan + rank scatter ----------------
__global__ __launch_bounds__(256) void dispatch_kernel(
    const int* __restrict__ eidx, const float* __restrict__ probs,
    int* __restrict__ counts, int* __restrict__ offs,
    int* __restrict__ rowtok, float* __restrict__ rowprob,
    int* __restrict__ tokslot) {
  __shared__ int chunkbase[NCHUNK][NEXP];
  __shared__ int tot[NEXP], off_s[NEXP];
  const int t = threadIdx.x;
  const int w = t >> 6, l = t & 63;

  for (int c = w; c < NCHUNK; c += 4) {
    const int e = eidx[c * 64 + l];
    #pragma unroll
    for (int xp = 0; xp < NEXP; ++xp) {
      const unsigned long long m = __ballot(e == xp);
      if (l == xp) chunkbase[c][xp] = __popcll(m);
    }
  }
  __syncthreads();

  if (t < NEXP) {
    int a = 0;
    for (int c = 0; c < NCHUNK; ++c) {
      const int v = chunkbase[c][t];
      chunkbase[c][t] = a;
      a += v;
    }
    tot[t] = a;
  }
  __syncthreads();
  if (t == 0) {
    int a = 0;
    for (int e = 0; e < NEXP; ++e) { off_s[e] = a; offs[e] = a; counts[e] = tot[e]; a += tot[e]; }
  }
  __syncthreads();

  for (int c = w; c < NCHUNK; c += 4) {
    const int s = c * 64 + l;
    const int e = eidx[s];
    unsigned long long mask_e = 0;
    #pragma unroll
    for (int xp = 0; xp < NEXP; ++xp) {
      const unsigned long long m = __ballot(e == xp);
      if (e == xp) mask_e = m;
    }
    const unsigned long long below = mask_e & ((1ull << l) - 1ull);
    const int pos = off_s[e] + chunkbase[c][e] + __popcll(below);
    rowtok[pos]  = s >> 1;
    rowprob[pos] = probs[s];
    tokslot[s]   = pos;
  }
}

// ---------------- standalone tconv (fallback path) ----------------
__global__ __launch_bounds__(256) void tconv_kernel(
    const float* __restrict__ in, unsigned short* __restrict__ out,
    int R, int C, int RB) {
  __shared__ float tile[64][65];
  const int r0 = blockIdx.y * 64, c0 = blockIdx.x * 64;
  const int t = threadIdx.x;
  const int tr = t >> 4;
  const int tc4 = (t & 15) * 4;
  #pragma unroll
  for (int i = 0; i < 4; ++i) {
    const int r = tr + i * 16;
    const f32x4 v = *(const f32x4*)&in[(size_t)(r0 + r) * C + c0 + tc4];
    tile[r][tc4 + 0] = v[0]; tile[r][tc4 + 1] = v[1];
    tile[r][tc4 + 2] = v[2]; tile[r][tc4 + 3] = v[3];
  }
  __syncthreads();
  const int eb  = r0 / RB;
  const int rm0 = r0 % RB;
  #pragma unroll
  for (int i = 0; i < 4; ++i) {
    const int c = tr + i * 16;
    ushort4 o;
    o.x = f2bf(tile[tc4 + 0][c]); o.y = f2bf(tile[tc4 + 1][c]);
    o.z = f2bf(tile[tc4 + 2][c]); o.w = f2bf(tile[tc4 + 3][c]);
    const size_t oidx = (size_t)eb * C * RB + (size_t)(c0 + c) * RB + rm0 + tc4;
    *(ushort4*)&out[oidx] = o;
  }
}

// ------- grouped GEMM1: 128x128, BK=32, 4-buffer depth-3 counted-vmcnt, T2+T1+T5, m-loop -------
__global__ __launch_bounds__(256) void gemm1_fast(
    const unsigned short* __restrict__ xb, const unsigned short* __restrict__ w1t,
    const int* __restrict__ rowtok, const int* __restrict__ counts,
    const int* __restrict__ offs, unsigned short* __restrict__ h1) {
  // T1 bijective XCD swizzle (G=1152, %8==0); decode 16 nx x 9 my x 8 e
  int wg = blockIdx.x;
  wg = (wg & 7) * (1152 / 8) + (wg >> 3);
  const int bx = wg & 15;
  const int rest = wg >> 4;
  const int by = rest % 9;
  const int e  = rest / 9;

  const int cnt = counts[e];
  const int n0  = bx * 128;
  const int seg = offs[e];

  __shared__ alignas(16) unsigned short Al[4][128 * 32];   // 32 KB
  __shared__ alignas(16) unsigned short Bl[4][128 * 32];   // 32 KB

  const int t  = threadIdx.x;
  const int l  = t & 63;
  const int w  = t >> 6;
  const int wr = w >> 1, wc = w & 1;
  const int lr = l & 15, hi = l >> 4;

  const int rowS = t >> 2;
  const int kc   = (((t & 3) ^ ((t >> 3) & 3)) * 8);    // T2 pre-swizzled global chunk
  const unsigned short* bptr0 = w1t + ((size_t)e * FFN + n0 + rowS) * HID + kc;
  const unsigned short* bptr1 = bptr0 + (size_t)64 * HID;
  const int ldst = (t & 192) * 8;
  const int koff = (hi ^ ((lr >> 1) & 3)) * 8;          // T2 swizzled read chunk
  const int NT = HID / 32;                              // 32 K-tiles

  bool firstm = true;
  for (int m0 = by * 128; m0 < cnt; m0 += 9 * 128) {
    if (!firstm) __syncthreads();                       // LDS reuse fence between m-iters
    firstm = false;

    const int ra0 = m0 + rowS      < cnt ? m0 + rowS      : cnt - 1;
    const int ra1 = m0 + rowS + 64 < cnt ? m0 + rowS + 64 : cnt - 1;
    const unsigned short* aptr0 = xb + (size_t)rowtok[seg + ra0] * HID + kc;
    const unsigned short* aptr1 = xb + (size_t)rowtok[seg + ra1] * HID + kc;

    f32x4 acc[4][4];
    #pragma unroll
    for (int i = 0; i < 4; ++i)
      #pragma unroll
      for (int j = 0; j < 4; ++j) acc[i][j] = (f32x4){0.f, 0.f, 0.f, 0.f};

    auto STAGE = [&](int b, int k0) {                   // exactly 4 uniform vmem ops/thread
      gload16(aptr0 + k0, &Al[b][ldst]);
      gload16(aptr1 + k0, &Al[b][ldst + 2048]);
      gload16(bptr0 + k0, &Bl[b][ldst]);
      gload16(bptr1 + k0, &Bl[b][ldst + 2048]);
    };
    auto COMPUTE = [&](int b) {
      short8 af[4], bfr[4];
      #pragma unroll
      for (int mi = 0; mi < 4; ++mi) af[mi]  = *(const short8*)&Al[b][(wr * 64 + mi * 16 + lr) * 32 + koff];
      #pragma unroll
      for (int ni = 0; ni < 4; ++ni) bfr[ni] = *(const short8*)&Bl[b][(wc * 64 + ni * 16 + lr) * 32 + koff];
      __builtin_amdgcn_s_setprio(1);                    // T5
      #pragma unroll
      for (int mi = 0; mi < 4; ++mi)
        #pragma unroll
        for (int ni = 0; ni < 4; ++ni)
          acc[mi][ni] = __builtin_amdgcn_mfma_f32_16x16x32_bf16(af[mi], bfr[ni], acc[mi][ni], 0, 0, 0);
      __builtin_amdgcn_s_setprio(0);
    };

    STAGE(0, 0);
    STAGE(1, 32);
    STAGE(2, 64);
    asm volatile("s_waitcnt vmcnt(8)" ::: "memory");    // tile0 landed; 1,2 in flight
    __builtin_amdgcn_s_barrier();
    __builtin_amdgcn_sched_barrier(0);
    int cur = 0;
    for (int tt = 0; tt < NT; ++tt) {
      if (tt + 3 < NT) STAGE((cur + 3) & 3, (tt + 3) * 32);
      COMPUTE(cur);
      if (tt + 1 < NT) {
        if (tt + 3 < NT)      asm volatile("s_waitcnt vmcnt(8)" ::: "memory");  // t+1 landed; t+2,t+3 fly
        else if (tt + 2 < NT) asm volatile("s_waitcnt vmcnt(4)" ::: "memory");  // t+1 landed; t+2 flies
        else                  asm volatile("s_waitcnt vmcnt(0)" ::: "memory");  // drain
        __builtin_amdgcn_s_barrier();
        __builtin_amdgcn_sched_barrier(0);
      }
      cur = (cur + 1) & 3;
    }

    #pragma unroll
    for (int mi = 0; mi < 4; ++mi) {
      #pragma unroll
      for (int r = 0; r < 4; ++r) {
        const int grow = m0 + wr * 64 + mi * 16 + hi * 4 + r;
        if (grow < cnt) {
          const size_t rowoff = (size_t)(seg + grow) * FFN + n0 + wc * 64 + lr;
          #pragma unroll
          for (int ni = 0; ni < 4; ++ni)
            h1[rowoff + ni * 16] = f2bf(gelu_f(acc[mi][ni][r]));
        }
      }
    }
  }
}

// ------- grouped GEMM2: 128x128, BK=32, 4-buffer depth-3 counted-vmcnt, T2+T1+T5, m-loop -------
template<int KS>
__global__ __launch_bounds__(256) void gemm2_fast(
    const unsigned short* __restrict__ h1, const unsigned short* __restrict__ w2t,
    const int* __restrict__ counts, const int* __restrict__ offs,
    unsigned short* __restrict__ y) {
  constexpr int G = 576 * KS;                           // 8 nx x 9 my x 8 e x KS; %8==0
  int wg = blockIdx.x;
  wg = (wg & 7) * (G / 8) + (wg >> 3);
  const int bx  = wg & 7;
  int rest = wg >> 3;
  const int by  = rest % 9;
  rest /= 9;
  const int e   = rest & 7;
  const int kz  = rest >> 3;

  const int cnt = counts[e];
  const int n0  = bx * 128;
  const int seg = offs[e];
  constexpr int KLEN = FFN / KS;
  const int kbase = kz * KLEN;

  __shared__ alignas(16) unsigned short Al[4][128 * 32];
  __shared__ alignas(16) unsigned short Bl[4][128 * 32];

  const int t  = threadIdx.x;
  const int l  = t & 63;
  const int w  = t >> 6;
  const int wr = w >> 1, wc = w & 1;
  const int lr = l & 15, hi = l >> 4;

  const int rowS = t >> 2;
  const int kc   = (((t & 3) ^ ((t >> 3) & 3)) * 8);
  const unsigned short* bptr0 = w2t + ((size_t)e * HID + n0 + rowS) * FFN + kbase + kc;
  const unsigned short* bptr1 = bptr0 + (size_t)64 * FFN;
  const int ldst = (t & 192) * 8;
  const int koff = (hi ^ ((lr >> 1) & 3)) * 8;
  const int NT = KLEN / 32;

  bool firstm = true;
  for (int m0 = by * 128; m0 < cnt; m0 += 9 * 128) {
    if (!firstm) __syncthreads();
    firstm = false;

    const int ra0 = m0 + rowS      < cnt ? m0 + rowS      : cnt - 1;
    const int ra1 = m0 + rowS + 64 < cnt ? m0 + rowS + 64 : cnt - 1;
    const unsigned short* aptr0 = h1 + (size_t)(seg + ra0) * FFN + kbase + kc;
    const unsigned short* aptr1 = h1 + (size_t)(seg + ra1) * FFN + kbase + kc;

    f32x4 acc[4][4];
    #pragma unroll
    for (int i = 0; i < 4; ++i)
      #pragma unroll
      for (int j = 0; j < 4; ++j) acc[i][j] = (f32x4){0.f, 0.f, 0.f, 0.f};

    auto STAGE = [&](int b, int k0) {
      gload16(aptr0 + k0, &Al[b][ldst]);
      gload16(aptr1 + k0, &Al[b][ldst + 2048]);
      gload16(bptr0 + k0, &Bl[b][ldst]);
      gload16(bptr1 + k0, &Bl[b][ldst + 2048]);
    };
    auto COMPUTE = [&](int b) {
      short8 af[4], bfr[4];
      #pragma unroll
      for (int mi = 0; mi < 4; ++mi) af[mi]  = *(const short8*)&Al[b][(wr * 64 + mi * 16 + lr) * 32 + koff];
      #pragma unroll
      for (int ni = 0; ni < 4; ++ni) bfr[ni] = *(const short8*)&Bl[b][(wc * 64 + ni * 16 + lr) * 32 + koff];
      __builtin_amdgcn_s_setprio(1);                    // T5
      #pragma unroll
      for (int mi = 0; mi < 4; ++mi)
        #pragma unroll
        for (int ni = 0; ni < 4; ++ni)
          acc[mi][ni] = __builtin_amdgcn_mfma_f32_16x16x32_bf16(af[mi], bfr[ni], acc[mi][ni], 0, 0, 0);
      __builtin_amdgcn_s_setprio(0);
    };

    STAGE(0, 0);
    STAGE(1, 32);
    STAGE(2, 64);
    asm volatile("s_waitcnt vmcnt(8)" ::: "memory");
    __builtin_amdgcn_s_barrier();
    __builtin_amdgcn_sched_barrier(0);
    int cur = 0;
    for (int tt = 0; tt < NT; ++tt) {
      if (tt + 3 < NT) STAGE((cur + 3) & 3, (tt + 3) * 32);
      COMPUTE(cur);
      if (tt + 1 < NT) {
        if (tt + 3 < NT)      asm volatile("s_waitcnt vmcnt(8)" ::: "memory");
        else if (tt + 2 < NT) asm volatile("s_waitcnt vmcnt(4)" ::: "memory");
        else                  asm volatile("s_waitcnt vmcnt(0)" ::: "memory");
        __builtin_amdgcn_s_barrier();
        __builtin_amdgcn_sched_barrier(0);
      }
      cur = (cur + 1) & 3;
    }

    #pragma unroll
    for (int mi = 0; mi < 4; ++mi) {
      #pragma unroll
      for (int r = 0; r < 4; ++r) {
        const int grow = m0 + wr * 64 + mi * 16 + hi * 4 + r;
        if (grow < cnt) {
          const int slot = seg + grow;
          unsigned short* yrow = y + ((size_t)kz * NSLOT + slot) * HID + n0 + wc * 64 + lr;
          #pragma unroll
          for (int ni = 0; ni < 4; ++ni)
            yrow[ni * 16] = f2bf(acc[mi][ni][r]);
        }
      }
    }
  }
}

// ---------------- combine: out[n] = p1*sum_kz y[kz][s1] + p2*sum_kz y[kz][s2] ----------------
template<int KS>
__global__ __launch_bounds__(256) void combine_kernel(
    const unsigned short* __restrict__ y, const int* __restrict__ tokslot,
    const float* __restrict__ probs, float* __restrict__ out) {
  const int n = blockIdx.x;
  const int c = threadIdx.x * 4;
  const int s1 = tokslot[n * 2 + 0], s2 = tokslot[n * 2 + 1];
  const float p1 = probs[n * 2 + 0], p2 = probs[n * 2 + 1];
  float r0 = 0.f, r1 = 0.f, r2 = 0.f, r3 = 0.f;
  #pragma unroll
  for (int kz = 0; kz < KS; ++kz) {
    const ushort4 a = *(const ushort4*)&y[((size_t)kz * NSLOT + s1) * HID + c];
    const ushort4 b = *(const ushort4*)&y[((size_t)kz * NSLOT + s2) * HID + c];
    r0 += p1 * bf2f(a.x) + p2 * bf2f(b.x);
    r1 += p1 * bf2f(a.y) + p2 * bf2f(b.y);
    r2 += p1 * bf2f(a.z) + p2 * bf2f(b.z);
    r3 += p1 * bf2f(a.w) + p2 * bf2f(b.w);
  }
  *(f32x4*)&out[(size_t)n * HID + c] = (f32x4){r0, r1, r2, r3};
}

// ---------------- tier-3: atomic-epilogue GEMM2 (round-7 proven, single-buffer) ----------------
__global__ __launch_bounds__(256) void gemm2_fast_atomic(
    const unsigned short* __restrict__ h1, const unsigned short* __restrict__ w2t,
    const int* __restrict__ rowtok, const float* __restrict__ rowprob,
    const int* __restrict__ counts, const int* __restrict__ offs,
    float* __restrict__ out) {
  const int e   = blockIdx.z;
  const int cnt = counts[e];
  const int m0  = blockIdx.y * 128;
  if (m0 >= cnt) return;
  const int n0  = blockIdx.x * 128;
  const int seg = offs[e];

  __shared__ alignas(16) unsigned short Al[128 * 32];
  __shared__ alignas(16) unsigned short Bl[128 * 32];

  const int t  = threadIdx.x;
  const int l  = t & 63;
  const int w  = t >> 6;
  const int wr = w >> 1, wc = w & 1;
  const int lr = l & 15, hi = l >> 4;

  const int rowS = t >> 2;
  const int kc   = (((t & 3) ^ ((t >> 3) & 3)) * 8);
  const int ra0 = m0 + rowS      < cnt ? m0 + rowS      : cnt - 1;
  const int ra1 = m0 + rowS + 64 < cnt ? m0 + rowS + 64 : cnt - 1;
  const unsigned short* aptr0 = h1 + (size_t)(seg + ra0) * FFN + kc;
  const unsigned short* aptr1 = h1 + (size_t)(seg + ra1) * FFN + kc;
  const unsigned short* bptr0 = w2t + ((size_t)e * HID + n0 + rowS)      * FFN + kc;
  const unsigned short* bptr1 = w2t + ((size_t)e * HID + n0 + rowS + 64) * FFN + kc;
  unsigned short* const ldsA0 = Al + (t & 192) * 8;
  unsigned short* const ldsB0 = Bl + (t & 192) * 8;
  const int koff = (hi ^ ((lr >> 1) & 3)) * 8;

  f32x4 acc[4][4];
  #pragma unroll
  for (int i = 0; i < 4; ++i)
    #pragma unroll
    for (int j = 0; j < 4; ++j) acc[i][j] = (f32x4){0.f, 0.f, 0.f, 0.f};

  for (int k0 = 0; k0 < FFN; k0 += 32) {
    gload16(aptr0 + k0, ldsA0);
    gload16(aptr1 + k0, ldsA0 + 2048);
    gload16(bptr0 + k0, ldsB0);
    gload16(bptr1 + k0, ldsB0 + 2048);
    __syncthreads();
    short8 af[4], bfr[4];
    #pragma unroll
    for (int mi = 0; mi < 4; ++mi) af[mi]  = *(const short8*)&Al[(wr * 64 + mi * 16 + lr) * 32 + koff];
    #pragma unroll
    for (int ni = 0; ni < 4; ++ni) bfr[ni] = *(const short8*)&Bl[(wc * 64 + ni * 16 + lr) * 32 + koff];
    #pragma unroll
    for (int mi = 0; mi < 4; ++mi)
      #pragma unroll
      for (int ni = 0; ni < 4; ++ni)
        acc[mi][ni] = __builtin_amdgcn_mfma_f32_16x16x32_bf16(af[mi], bfr[ni], acc[mi][ni], 0, 0, 0);
    __syncthreads();
  }

  #pragma unroll
  for (int mi = 0; mi < 4; ++mi) {
    #pragma unroll
    for (int r = 0; r < 4; ++r) {
      const int grow = m0 + wr * 64 + mi * 16 + hi * 4 + r;
      if (grow < cnt) {
        const int slot = seg + grow;
        const int tok  = rowtok[slot];
        const float p  = rowprob[slot];
        #pragma unroll
        for (int ni = 0; ni < 4; ++ni)
          atomicAdd(&out[(size_t)tok * HID + n0 + wc * 64 + ni * 16 + lr], p * acc[mi][ni][r]);
      }
    }
  }
}

// ================= tier-4 fallback (round-0 proven 64x64 GEMMs) =================
__global__ __launch_bounds__(256) void gemm1_old(
    const float* __restrict__ x, const float* __restrict__ w1,
    const int* __restrict__ rowtok, const int* __restrict__ counts,
    const int* __restrict__ offs, unsigned short* __restrict__ h1) {
  const int e   = blockIdx.z;
  const int cnt = counts[e];
  const int m0  = blockIdx.y * 64;
  if (m0 >= cnt) return;
  const int n0  = blockIdx.x * 64;
  const int seg = offs[e];
  __shared__ unsigned short Al[64 * 40];
  __shared__ unsigned short Bl[64 * 40];
  const int t  = threadIdx.x;
  const int l  = t & 63;
  const int wv = t >> 6;
  const int wr = wv >> 1, wc = wv & 1;
  const int am  = t >> 2;
  const int akb = (t & 3) * 8;
  const int amg = m0 + am;
  const bool aval = (amg < cnt);
  const float* aptr = aval ? (x + (size_t)rowtok[seg + amg] * HID + akb) : x;
  const int bn  = t & 63;
  const int bkg = (t >> 6) * 8;
  const float* bptr = w1 + (size_t)e * FFN + n0 + bn;
  f32x4 acc[2][2];
  #pragma unroll
  for (int i = 0; i < 2; ++i)
    #pragma unroll
    for (int j = 0; j < 2; ++j) acc[i][j] = (f32x4){0.f, 0.f, 0.f, 0.f};
  const int kreg = (l >> 4) * 8;
  const int lr   = l & 15;
  for (int k0 = 0; k0 < HID; k0 += 32) {
    short8 av = (short8){0,0,0,0,0,0,0,0};
    if (aval) {
      const f32x4 v0 = *(const f32x4*)(aptr + k0);
      const f32x4 v1 = *(const f32x4*)(aptr + k0 + 4);
      #pragma unroll
      for (int j = 0; j < 4; ++j) { av[j] = (short)f2bf(v0[j]); av[4 + j] = (short)f2bf(v1[j]); }
    }
    *(short8*)&Al[am * 40 + akb] = av;
    short8 bv;
    #pragma unroll
    for (int j = 0; j < 8; ++j) bv[j] = (short)f2bf(bptr[(size_t)(k0 + bkg + j) * WROW]);
    *(short8*)&Bl[bn * 40 + bkg] = bv;
    __syncthreads();
    short8 af[2], bfr[2];
    #pragma unroll
    for (int mi = 0; mi < 2; ++mi) af[mi]  = *(const short8*)&Al[(wr * 32 + mi * 16 + lr) * 40 + kreg];
    #pragma unroll
    for (int ni = 0; ni < 2; ++ni) bfr[ni] = *(const short8*)&Bl[(wc * 32 + ni * 16 + lr) * 40 + kreg];
    #pragma unroll
    for (int mi = 0; mi < 2; ++mi)
      #pragma unroll
      for (int ni = 0; ni < 2; ++ni)
        acc[mi][ni] = __builtin_amdgcn_mfma_f32_16x16x32_bf16(af[mi], bfr[ni], acc[mi][ni], 0, 0, 0);
    __syncthreads();
  }
  const int kq = l >> 4;
  #pragma unroll
  for (int mi = 0; mi < 2; ++mi) {
    #pragma unroll
    for (int r = 0; r < 4; ++r) {
      const int grow = m0 + wr * 32 + mi * 16 + kq * 4 + r;
      if (grow < cnt) {
        #pragma unroll
        for (int ni = 0; ni < 2; ++ni) {
          const float v = acc[mi][ni][r];
          const float g = 0.5f * v * (1.0f + erff(v * 0.70710678118654752f));
          h1[(size_t)(seg + grow) * FFN + n0 + wc * 32 + ni * 16 + lr] = f2bf(g);
        }
      }
    }
  }
}

__global__ __launch_bounds__(256) void gemm2_old(
    const unsigned short* __restrict__ h1, const float* __restrict__ w2,
    const int* __restrict__ rowtok, const float* __restrict__ rowprob,
    const int* __restrict__ counts, const int* __restrict__ offs,
    float* __restrict__ out) {
  const int e   = blockIdx.z;
  const int cnt = counts[e];
  const int m0  = blockIdx.y * 64;
  if (m0 >= cnt) return;
  const int n0  = blockIdx.x * 64;
  const int seg = offs[e];
  __shared__ unsigned short Al[64 * 40];
  __shared__ unsigned short Bl[64 * 40];
  const int t  = threadIdx.x;
  const int l  = t & 63;
  const int wv = t >> 6;
  const int wr = wv >> 1, wc = wv & 1;
  const int am  = t >> 2;
  const int akb = (t & 3) * 8;
  const int amg = m0 + am;
  const bool aval = (amg < cnt);
  const unsigned short* aptr = aval ? (h1 + (size_t)(seg + amg) * FFN + akb) : h1;
  const int bn  = t & 63;
  const int bkg = (t >> 6) * 8;
  const float* bptr = w2 + (size_t)e * FFN * HID + n0 + bn;
  f32x4 acc[2][2];
  #pragma unroll
  for (int i = 0; i < 2; ++i)
    #pragma unroll
    for (int j = 0; j < 2; ++j) acc[i][j] = (f32x4){0.f, 0.f, 0.f, 0.f};
  const int kreg = (l >> 4) * 8;
  const int lr   = l & 15;
  for (int k0 = 0; k0 < FFN; k0 += 32) {
    short8 av = (short8){0,0,0,0,0,0,0,0};
    if (aval) av = *(const short8*)(aptr + k0);
    *(short8*)&Al[am * 40 + akb] = av;
    short8 bv;
    #pragma unroll
    for (int j = 0; j < 8; ++j) bv[j] = (short)f2bf(bptr[(size_t)(k0 + bkg + j) * HID]);
    *(short8*)&Bl[bn * 40 + bkg] = bv;
    __syncthreads();
    short8 af[2], bfr[2];
    #pragma unroll
    for (int mi = 0; mi < 2; ++mi) af[mi]  = *(const short8*)&Al[(wr * 32 + mi * 16 + lr) * 40 + kreg];
    #pragma unroll
    for (int ni = 0; ni < 2; ++ni) bfr[ni] = *(const short8*)&Bl[(wc * 32 + ni * 16 + lr) * 40 + kreg];
    #pragma unroll
    for (int mi = 0; mi < 2; ++mi)
      #pragma unroll
      for (int ni = 0; ni < 2; ++ni)
        acc[mi][ni] = __builtin_amdgcn_mfma_f32_16x16x32_bf16(af[mi], bfr[ni], acc[mi][ni], 0, 0, 0);
    __syncthreads();
  }
  const int kq = l >> 4;
  #pragma unroll
  for (int mi = 0; mi < 2; ++mi) {
    #pragma unroll
    for (int r = 0; r < 4; ++r) {
      const int grow = m0 + wr * 32 + mi * 16 + kq * 4 + r;
      if (grow < cnt) {
        const int slot = seg + grow;
        const int tok  = rowtok[slot];
        const float p  = rowprob[slot];
        #pragma unroll
        for (int ni = 0; ni < 2; ++ni)
          atomicAdd(&out[(size_t)tok * HID + n0 + wc * 32 + ni * 16 + lr], p * acc[mi][ni][r]);
      }
    }
  }
}

extern "C" void kernel_launch(void* const* d_in, const int* in_sizes, int n_in,
                              void* d_out, int out_size, void* d_ws, size_t ws_size,
                              hipStream_t stream) {
  const float* x  = (const float*)d_in[0];
  const float* rw = (const float*)d_in[1];
  const float* w1 = (const float*)d_in[2];
  const float* w2 = (const float*)d_in[3];
  float* out = (float*)d_out;

  // ws layout
  int*   counts  = (int*)d_ws;                 // 8
  int*   offs    = counts + 8;                 // 8
  int*   tokslot = counts + 16;                // NSLOT
  int*   eidx    = tokslot + NSLOT;            // NSLOT
  float* probs   = (float*)(eidx + NSLOT);     // NSLOT
  int*   rowtok  = (int*)(probs + NSLOT);      // NSLOT
  float* rowprob = (float*)(rowtok + NSLOT);   // NSLOT
  unsigned short* h1  = (unsigned short*)(rowprob + NSLOT);  // 32 MiB
  unsigned short* xb  = h1 + (size_t)NSLOT * FFN;            // 8 MiB
  unsigned short* wt  = xb + (size_t)N_TOK * HID;            // 32 MiB (w1t)
  unsigned short* wt2 = wt + (size_t)WROW * HID;             // seq path: y; merged: w2t
  unsigned short* ymg = wt2 + (size_t)WROW * HID;            // merged path: y (16 MiB, KS=1)

  const size_t need_base   = (size_t)((char*)wt2 - (char*)d_ws);       // ~76 MiB
  const size_t need_seq_y1 = need_base + (size_t)NSLOT * HID * 2;      // +16 MiB
  const size_t need_mrg_y1 = need_base + (size_t)WROW * HID * 2        // +32 MiB (w2t)
                             + (size_t)NSLOT * HID * 2;                // +16 MiB (y)
  const bool fast = (ws_size >= need_base);

  if (fast && ws_size >= need_mrg_y1) {
    // merged router + both tconvs, then dispatch
    prep_kernel<<<N_TOK / 4 + 8192, 256, 0, stream>>>(x, rw, eidx, probs, xb, w1, w2, wt, wt2);
    dispatch_kernel<<<1, 256, 0, stream>>>(eidx, probs, counts, offs, rowtok, rowprob, tokslot);
    gemm1_fast<<<1152, 256, 0, stream>>>(xb, wt, rowtok, counts, offs, h1);
    gemm2_fast<1><<<576, 256, 0, stream>>>(h1, wt2, counts, offs, ymg);
    combine_kernel<1><<<N_TOK, 256, 0, stream>>>(ymg, tokslot, probs, out);
  } else if (fast) {
    // sequential tconv, wt reused
    prep_kernel<<<N_TOK / 4, 256, 0, stream>>>(x, rw, eidx, probs, xb, w1, w2, wt, wt);  // router only (grid < 1024+)
    dispatch_kernel<<<1, 256, 0, stream>>>(eidx, probs, counts, offs, rowtok, rowprob, tokslot);
    tconv_kernel<<<dim3(WROW / 64, HID / 64), 256, 0, stream>>>(w1, wt, HID, WROW, HID);
    gemm1_fast<<<1152, 256, 0, stream>>>(xb, wt, rowtok, counts, offs, h1);
    tconv_kernel<<<dim3(HID / 64, WROW / 64), 256, 0, stream>>>(w2, wt, WROW, HID, FFN);
    if (ws_size >= need_seq_y1) {
      gemm2_fast<1><<<576, 256, 0, stream>>>(h1, wt, counts, offs, wt2);
      combine_kernel<1><<<N_TOK, 256, 0, stream>>>(wt2, tokslot, probs, out);
    } else {
      hipMemsetAsync(d_out, 0, (size_t)out_size * sizeof(float), stream);
      gemm2_fast_atomic<<<dim3(HID / 128, NSLOT / 128, NEXP), 256, 0, stream>>>(h1, wt, rowtok, rowprob, counts, offs, out);
    }
  } else {
    hipMemsetAsync(d_out, 0, (size_t)out_size * sizeof(float), stream);
    router_old:
    {
      prep_kernel<<<N_TOK / 4, 256, 0, stream>>>(x, rw, eidx, probs, nullptr, w1, w2, nullptr, nullptr);
      dispatch_kernel<<<1, 256, 0, stream>>>(eidx, probs, counts, offs, rowtok, rowprob, tokslot);
    }
    gemm1_old<<<dim3(FFN / 64, NSLOT / 64, NEXP), 256, 0, stream>>>(x, w1, rowtok, counts, offs, h1);
    gemm2_old<<<dim3(HID / 64, NSLOT / 64, NEXP), 256, 0, stream>>>(h1, w2, rowtok, rowprob, counts, offs, out);
  }
}

// Round 13
// 202.272 us; speedup vs baseline: 1.1720x; 1.1720x over previous
//
#include <hip/hip_runtime.h>
#include <hip/hip_bf16.h>
#include <math.h>

#define N_TOK 4096
#define HID   1024
#define FFN   2048
#define NEXP  8
#define WROW  (NEXP*FFN)    /* 16384: row stride of w1 */
#define NSLOT (N_TOK*2)     /* 8192 (token,k) slots    */
#define NCHUNK (NSLOT/64)   /* 128 ballot chunks       */

typedef __attribute__((ext_vector_type(4))) float f32x4;
typedef __attribute__((ext_vector_type(8))) short short8;

__device__ inline unsigned short f2bf(float f) {
  union { float f; unsigned u; } v; v.f = f;
  unsigned r = v.u + 0x7fffu + ((v.u >> 16) & 1u);   // RNE to bf16
  return (unsigned short)(r >> 16);
}
__device__ __forceinline__ float bf2f(unsigned short u) {
  union { unsigned u; float f; } v; v.u = ((unsigned)u) << 16; return v.f;
}

// tanh-form GELU: |err| vs exact erf-gelu <= ~3e-3, sub-ulp of bf16 storage of h1.
__device__ __forceinline__ float gelu_f(float v) {
  const float u = 1.5957691216057308f * v + 0.07135481627f * (v * v * v);
  return v / (1.f + __expf(-u));
}

__device__ __forceinline__ void gload16(const void* g, void* l) {
  __builtin_amdgcn_global_load_lds((const __attribute__((address_space(1))) void*)g,
                                   (__attribute__((address_space(3))) void*)l, 16, 0, 0);
}

// Proven config (r11 = 206.8us best): 128^2 tile, BK=32, 3-buffer depth-2
// vmcnt(4), T1 XCD-swizzle, T2 chunk-swizzle (conflicts 4.39M->0), T5 setprio.
// r9: 256^2 tile -> 1 block/CU -> regression. r12: depth-3 (64KB LDS) -> 1
// block/CU -> regression. Cross-block overlap at 2-3 blocks/CU is the win
// condition for this M=8192/K=1-2K grouped shape; do not trade it away.

// ---------------- prep: router (blocks 0..1023) + both tconvs (blocks 1024..9215) ----------------
__global__ __launch_bounds__(256) void prep_kernel(
    const float* __restrict__ x, const float* __restrict__ rw,
    int* __restrict__ eidx, float* __restrict__ probs, unsigned short* __restrict__ xb,
    const float* __restrict__ w1, const float* __restrict__ w2,
    unsigned short* __restrict__ w1t, unsigned short* __restrict__ w2t) {
  __shared__ float rwT[NEXP][HID];   // 32 KB (router)
  __shared__ float tile[64][65];     // 16.6 KB (tconv)
  const int t = threadIdx.x;

  if (blockIdx.x < N_TOK / 4) {
    // ---- router: 4 tokens/block, rw^T in LDS, no atomics ----
    #pragma unroll
    for (int it = 0; it < 8; ++it) {
      const int flat = t * 4 + it * 1024;
      const f32x4 v = *(const f32x4*)&rw[flat];
      #pragma unroll
      for (int j = 0; j < 4; ++j) rwT[(flat + j) & 7][(flat + j) >> 3] = v[j];
    }
    __syncthreads();

    const int w = t >> 6, l = t & 63;
    const int n = blockIdx.x * 4 + w;
    const float* xr = x + (size_t)n * HID;
    float acc[NEXP];
    #pragma unroll
    for (int e = 0; e < NEXP; ++e) acc[e] = 0.f;

    #pragma unroll
    for (int j = 0; j < 4; ++j) {
      const int i = l * 4 + j * 256;
      const f32x4 xv = *(const f32x4*)&xr[i];
      if (xb) {
        ushort4 o;
        o.x = f2bf(xv[0]); o.y = f2bf(xv[1]); o.z = f2bf(xv[2]); o.w = f2bf(xv[3]);
        *(ushort4*)&xb[(size_t)n * HID + i] = o;
      }
      #pragma unroll
      for (int e = 0; e < NEXP; ++e) {
        const f32x4 wv = *(const f32x4*)&rwT[e][i];
        acc[e] += xv[0] * wv[0] + xv[1] * wv[1] + xv[2] * wv[2] + xv[3] * wv[3];
      }
    }
    #pragma unroll
    for (int e = 0; e < NEXP; ++e) {
      float s = acc[e];
      #pragma unroll
      for (int off = 32; off; off >>= 1) s += __shfl_xor(s, off);
      acc[e] = s;
    }
    if (l == 0) {
      float m = acc[0];
      #pragma unroll
      for (int e = 1; e < NEXP; ++e) m = fmaxf(m, acc[e]);
      float p[NEXP]; float den = 0.f;
      #pragma unroll
      for (int e = 0; e < NEXP; ++e) { p[e] = expf(acc[e] - m); den += p[e]; }
      const float inv = 1.f / den;
      int e1 = 0; float b1 = -1.f;
      #pragma unroll
      for (int e = 0; e < NEXP; ++e) if (p[e] > b1) { b1 = p[e]; e1 = e; }
      int e2 = 0; float b2 = -1.f;
      #pragma unroll
      for (int e = 0; e < NEXP; ++e) if (e != e1 && p[e] > b2) { b2 = p[e]; e2 = e; }
      eidx[n * 2 + 0] = e1; eidx[n * 2 + 1] = e2;
      probs[n * 2 + 0] = b1 * inv; probs[n * 2 + 1] = b2 * inv;
    }
    return;
  }

  // ---- tconv: in [R][C] fp32 -> out bf16 [r/RB][C][r%RB] ----
  int b = blockIdx.x - N_TOK / 4;
  const float* in; unsigned short* out; int C, RB, r0, c0;
  if (b < 4096) {                 // w1 [1024][16384] -> w1t [16384][1024]
    in = w1; out = w1t; C = WROW; RB = HID;
    c0 = (b & 255) * 64; r0 = (b >> 8) * 64;
  } else {                        // w2 [16384][1024] -> w2t [8][1024][2048]
    b -= 4096;
    in = w2; out = w2t; C = HID; RB = FFN;
    c0 = (b & 15) * 64; r0 = (b >> 4) * 64;
  }
  const int tr = t >> 4;
  const int tc4 = (t & 15) * 4;
  #pragma unroll
  for (int i = 0; i < 4; ++i) {
    const int r = tr + i * 16;
    const f32x4 v = *(const f32x4*)&in[(size_t)(r0 + r) * C + c0 + tc4];
    tile[r][tc4 + 0] = v[0]; tile[r][tc4 + 1] = v[1];
    tile[r][tc4 + 2] = v[2]; tile[r][tc4 + 3] = v[3];
  }
  __syncthreads();
  const int eb  = r0 / RB;
  const int rm0 = r0 % RB;
  #pragma unroll
  for (int i = 0; i < 4; ++i) {
    const int c = tr + i * 16;
    ushort4 o;
    o.x = f2bf(tile[tc4 + 0][c]); o.y = f2bf(tile[tc4 + 1][c]);
    o.z = f2bf(tile[tc4 + 2][c]); o.w = f2bf(tile[tc4 + 3][c]);
    const size_t oidx = (size_t)eb * C * RB + (size_t)(c0 + c) * RB + rm0 + tc4;
    *(ushort4*)&out[oidx] = o;
  }
}

// ---------------- dispatch: single block; ballot histogram + scan + rank scatter ----------------
__global__ __launch_bounds__(256) void dispatch_kernel(
    const int* __restrict__ eidx, const float* __restrict__ probs,
    int* __restrict__ counts, int* __restrict__ offs,
    int* __restrict__ rowtok, float* __restrict__ rowprob,
    int* __restrict__ tokslot) {
  __shared__ int chunkbase[NCHUNK][NEXP];
  __shared__ int tot[NEXP], off_s[NEXP];
  const int t = threadIdx.x;
  const int w = t >> 6, l = t & 63;

  for (int c = w; c < NCHUNK; c += 4) {
    const int e = eidx[c * 64 + l];
    #pragma unroll
    for (int xp = 0; xp < NEXP; ++xp) {
      const unsigned long long m = __ballot(e == xp);
      if (l == xp) chunkbase[c][xp] = __popcll(m);
    }
  }
  __syncthreads();

  if (t < NEXP) {
    int a = 0;
    for (int c = 0; c < NCHUNK; ++c) {
      const int v = chunkbase[c][t];
      chunkbase[c][t] = a;
      a += v;
    }
    tot[t] = a;
  }
  __syncthreads();
  if (t == 0) {
    int a = 0;
    for (int e = 0; e < NEXP; ++e) { off_s[e] = a; offs[e] = a; counts[e] = tot[e]; a += tot[e]; }
  }
  __syncthreads();

  for (int c = w; c < NCHUNK; c += 4) {
    const int s = c * 64 + l;
    const int e = eidx[s];
    unsigned long long mask_e = 0;
    #pragma unroll
    for (int xp = 0; xp < NEXP; ++xp) {
      const unsigned long long m = __ballot(e == xp);
      if (e == xp) mask_e = m;
    }
    const unsigned long long below = mask_e & ((1ull << l) - 1ull);
    const int pos = off_s[e] + chunkbase[c][e] + __popcll(below);
    rowtok[pos]  = s >> 1;
    rowprob[pos] = probs[s];
    tokslot[s]   = pos;
  }
}

// ---------------- standalone tconv (seq path) ----------------
__global__ __launch_bounds__(256) void tconv_kernel(
    const float* __restrict__ in, unsigned short* __restrict__ out,
    int R, int C, int RB) {
  __shared__ float tile[64][65];
  const int r0 = blockIdx.y * 64, c0 = blockIdx.x * 64;
  const int t = threadIdx.x;
  const int tr = t >> 4;
  const int tc4 = (t & 15) * 4;
  #pragma unroll
  for (int i = 0; i < 4; ++i) {
    const int r = tr + i * 16;
    const f32x4 v = *(const f32x4*)&in[(size_t)(r0 + r) * C + c0 + tc4];
    tile[r][tc4 + 0] = v[0]; tile[r][tc4 + 1] = v[1];
    tile[r][tc4 + 2] = v[2]; tile[r][tc4 + 3] = v[3];
  }
  __syncthreads();
  const int eb  = r0 / RB;
  const int rm0 = r0 % RB;
  #pragma unroll
  for (int i = 0; i < 4; ++i) {
    const int c = tr + i * 16;
    ushort4 o;
    o.x = f2bf(tile[tc4 + 0][c]); o.y = f2bf(tile[tc4 + 1][c]);
    o.z = f2bf(tile[tc4 + 2][c]); o.w = f2bf(tile[tc4 + 3][c]);
    const size_t oidx = (size_t)eb * C * RB + (size_t)(c0 + c) * RB + rm0 + tc4;
    *(ushort4*)&out[oidx] = o;
  }
}

// ------- grouped GEMM1: 128x128, BK=32, 3-buffer depth-2 counted-vmcnt, T2+T1+T5, m-loop -------
__global__ __launch_bounds__(256) void gemm1_fast(
    const unsigned short* __restrict__ xb, const unsigned short* __restrict__ w1t,
    const int* __restrict__ rowtok, const int* __restrict__ counts,
    const int* __restrict__ offs, unsigned short* __restrict__ h1) {
  // T1 bijective XCD swizzle (G=1152, %8==0); decode 16 nx x 9 my x 8 e
  int wg = blockIdx.x;
  wg = (wg & 7) * (1152 / 8) + (wg >> 3);
  const int bx = wg & 15;
  const int rest = wg >> 4;
  const int by = rest % 9;
  const int e  = rest / 9;

  const int cnt = counts[e];
  const int n0  = bx * 128;
  const int seg = offs[e];

  __shared__ alignas(16) unsigned short Al[3][128 * 32];
  __shared__ alignas(16) unsigned short Bl[3][128 * 32];

  const int t  = threadIdx.x;
  const int l  = t & 63;
  const int w  = t >> 6;
  const int wr = w >> 1, wc = w & 1;
  const int lr = l & 15, hi = l >> 4;

  const int rowS = t >> 2;
  const int kc   = (((t & 3) ^ ((t >> 3) & 3)) * 8);    // T2 pre-swizzled global chunk
  const unsigned short* bptr0 = w1t + ((size_t)e * FFN + n0 + rowS) * HID + kc;
  const unsigned short* bptr1 = bptr0 + (size_t)64 * HID;
  const int ldst = (t & 192) * 8;
  const int koff = (hi ^ ((lr >> 1) & 3)) * 8;          // T2 swizzled read chunk
  const int NT = HID / 32;                              // 32 K-tiles

  bool firstm = true;
  for (int m0 = by * 128; m0 < cnt; m0 += 9 * 128) {
    if (!firstm) __syncthreads();                       // LDS reuse fence between m-iters
    firstm = false;

    const int ra0 = m0 + rowS      < cnt ? m0 + rowS      : cnt - 1;
    const int ra1 = m0 + rowS + 64 < cnt ? m0 + rowS + 64 : cnt - 1;
    const unsigned short* aptr0 = xb + (size_t)rowtok[seg + ra0] * HID + kc;
    const unsigned short* aptr1 = xb + (size_t)rowtok[seg + ra1] * HID + kc;

    f32x4 acc[4][4];
    #pragma unroll
    for (int i = 0; i < 4; ++i)
      #pragma unroll
      for (int j = 0; j < 4; ++j) acc[i][j] = (f32x4){0.f, 0.f, 0.f, 0.f};

    auto STAGE = [&](int b, int k0) {                   // exactly 4 uniform vmem ops/thread
      gload16(aptr0 + k0, &Al[b][ldst]);
      gload16(aptr1 + k0, &Al[b][ldst + 2048]);
      gload16(bptr0 + k0, &Bl[b][ldst]);
      gload16(bptr1 + k0, &Bl[b][ldst + 2048]);
    };
    auto COMPUTE = [&](int b) {
      short8 af[4], bfr[4];
      #pragma unroll
      for (int mi = 0; mi < 4; ++mi) af[mi]  = *(const short8*)&Al[b][(wr * 64 + mi * 16 + lr) * 32 + koff];
      #pragma unroll
      for (int ni = 0; ni < 4; ++ni) bfr[ni] = *(const short8*)&Bl[b][(wc * 64 + ni * 16 + lr) * 32 + koff];
      __builtin_amdgcn_s_setprio(1);                    // T5
      #pragma unroll
      for (int mi = 0; mi < 4; ++mi)
        #pragma unroll
        for (int ni = 0; ni < 4; ++ni)
          acc[mi][ni] = __builtin_amdgcn_mfma_f32_16x16x32_bf16(af[mi], bfr[ni], acc[mi][ni], 0, 0, 0);
      __builtin_amdgcn_s_setprio(0);
    };

    STAGE(0, 0);
    STAGE(1, 32);
    asm volatile("s_waitcnt vmcnt(4)" ::: "memory");    // tile0 landed; tile1 in flight
    __builtin_amdgcn_s_barrier();
    __builtin_amdgcn_sched_barrier(0);
    int cur = 0;
    for (int tt = 0; tt < NT; ++tt) {
      if (tt + 2 < NT) {
        int b2 = cur + 2; if (b2 >= 3) b2 -= 3;
        STAGE(b2, (tt + 2) * 32);
      }
      COMPUTE(cur);
      if (tt + 1 < NT) {
        if (tt + 2 < NT) asm volatile("s_waitcnt vmcnt(4)" ::: "memory");
        else             asm volatile("s_waitcnt vmcnt(0)" ::: "memory");
        __builtin_amdgcn_s_barrier();
        __builtin_amdgcn_sched_barrier(0);
      }
      ++cur; if (cur == 3) cur = 0;
    }

    #pragma unroll
    for (int mi = 0; mi < 4; ++mi) {
      #pragma unroll
      for (int r = 0; r < 4; ++r) {
        const int grow = m0 + wr * 64 + mi * 16 + hi * 4 + r;
        if (grow < cnt) {
          const size_t rowoff = (size_t)(seg + grow) * FFN + n0 + wc * 64 + lr;
          #pragma unroll
          for (int ni = 0; ni < 4; ++ni)
            h1[rowoff + ni * 16] = f2bf(gelu_f(acc[mi][ni][r]));
        }
      }
    }
  }
}

// ------- grouped GEMM2: 128x128, BK=32, 3-buffer depth-2 counted-vmcnt, T2+T1+T5, m-loop -------
template<int KS>
__global__ __launch_bounds__(256) void gemm2_fast(
    const unsigned short* __restrict__ h1, const unsigned short* __restrict__ w2t,
    const int* __restrict__ counts, const int* __restrict__ offs,
    unsigned short* __restrict__ y) {
  constexpr int G = 576 * KS;                           // 8 nx x 9 my x 8 e x KS; %8==0
  int wg = blockIdx.x;
  wg = (wg & 7) * (G / 8) + (wg >> 3);
  const int bx  = wg & 7;
  int rest = wg >> 3;
  const int by  = rest % 9;
  rest /= 9;
  const int e   = rest & 7;
  const int kz  = rest >> 3;

  const int cnt = counts[e];
  const int n0  = bx * 128;
  const int seg = offs[e];
  constexpr int KLEN = FFN / KS;
  const int kbase = kz * KLEN;

  __shared__ alignas(16) unsigned short Al[3][128 * 32];
  __shared__ alignas(16) unsigned short Bl[3][128 * 32];

  const int t  = threadIdx.x;
  const int l  = t & 63;
  const int w  = t >> 6;
  const int wr = w >> 1, wc = w & 1;
  const int lr = l & 15, hi = l >> 4;

  const int rowS = t >> 2;
  const int kc   = (((t & 3) ^ ((t >> 3) & 3)) * 8);
  const unsigned short* bptr0 = w2t + ((size_t)e * HID + n0 + rowS) * FFN + kbase + kc;
  const unsigned short* bptr1 = bptr0 + (size_t)64 * FFN;
  const int ldst = (t & 192) * 8;
  const int koff = (hi ^ ((lr >> 1) & 3)) * 8;
  const int NT = KLEN / 32;

  bool firstm = true;
  for (int m0 = by * 128; m0 < cnt; m0 += 9 * 128) {
    if (!firstm) __syncthreads();
    firstm = false;

    const int ra0 = m0 + rowS      < cnt ? m0 + rowS      : cnt - 1;
    const int ra1 = m0 + rowS + 64 < cnt ? m0 + rowS + 64 : cnt - 1;
    const unsigned short* aptr0 = h1 + (size_t)(seg + ra0) * FFN + kbase + kc;
    const unsigned short* aptr1 = h1 + (size_t)(seg + ra1) * FFN + kbase + kc;

    f32x4 acc[4][4];
    #pragma unroll
    for (int i = 0; i < 4; ++i)
      #pragma unroll
      for (int j = 0; j < 4; ++j) acc[i][j] = (f32x4){0.f, 0.f, 0.f, 0.f};

    auto STAGE = [&](int b, int k0) {
      gload16(aptr0 + k0, &Al[b][ldst]);
      gload16(aptr1 + k0, &Al[b][ldst + 2048]);
      gload16(bptr0 + k0, &Bl[b][ldst]);
      gload16(bptr1 + k0, &Bl[b][ldst + 2048]);
    };
    auto COMPUTE = [&](int b) {
      short8 af[4], bfr[4];
      #pragma unroll
      for (int mi = 0; mi < 4; ++mi) af[mi]  = *(const short8*)&Al[b][(wr * 64 + mi * 16 + lr) * 32 + koff];
      #pragma unroll
      for (int ni = 0; ni < 4; ++ni) bfr[ni] = *(const short8*)&Bl[b][(wc * 64 + ni * 16 + lr) * 32 + koff];
      __builtin_amdgcn_s_setprio(1);                    // T5
      #pragma unroll
      for (int mi = 0; mi < 4; ++mi)
        #pragma unroll
        for (int ni = 0; ni < 4; ++ni)
          acc[mi][ni] = __builtin_amdgcn_mfma_f32_16x16x32_bf16(af[mi], bfr[ni], acc[mi][ni], 0, 0, 0);
      __builtin_amdgcn_s_setprio(0);
    };

    STAGE(0, 0);
    STAGE(1, 32);
    asm volatile("s_waitcnt vmcnt(4)" ::: "memory");
    __builtin_amdgcn_s_barrier();
    __builtin_amdgcn_sched_barrier(0);
    int cur = 0;
    for (int tt = 0; tt < NT; ++tt) {
      if (tt + 2 < NT) {
        int b2 = cur + 2; if (b2 >= 3) b2 -= 3;
        STAGE(b2, (tt + 2) * 32);
      }
      COMPUTE(cur);
      if (tt + 1 < NT) {
        if (tt + 2 < NT) asm volatile("s_waitcnt vmcnt(4)" ::: "memory");
        else             asm volatile("s_waitcnt vmcnt(0)" ::: "memory");
        __builtin_amdgcn_s_barrier();
        __builtin_amdgcn_sched_barrier(0);
      }
      ++cur; if (cur == 3) cur = 0;
    }

    #pragma unroll
    for (int mi = 0; mi < 4; ++mi) {
      #pragma unroll
      for (int r = 0; r < 4; ++r) {
        const int grow = m0 + wr * 64 + mi * 16 + hi * 4 + r;
        if (grow < cnt) {
          const int slot = seg + grow;
          unsigned short* yrow = y + ((size_t)kz * NSLOT + slot) * HID + n0 + wc * 64 + lr;
          #pragma unroll
          for (int ni = 0; ni < 4; ++ni)
            yrow[ni * 16] = f2bf(acc[mi][ni][r]);
        }
      }
    }
  }
}

// ---------------- combine: out[n] = p1*sum_kz y[kz][s1] + p2*sum_kz y[kz][s2] ----------------
template<int KS>
__global__ __launch_bounds__(256) void combine_kernel(
    const unsigned short* __restrict__ y, const int* __restrict__ tokslot,
    const float* __restrict__ probs, float* __restrict__ out) {
  const int n = blockIdx.x;
  const int c = threadIdx.x * 4;
  const int s1 = tokslot[n * 2 + 0], s2 = tokslot[n * 2 + 1];
  const float p1 = probs[n * 2 + 0], p2 = probs[n * 2 + 1];
  float r0 = 0.f, r1 = 0.f, r2 = 0.f, r3 = 0.f;
  #pragma unroll
  for (int kz = 0; kz < KS; ++kz) {
    const ushort4 a = *(const ushort4*)&y[((size_t)kz * NSLOT + s1) * HID + c];
    const ushort4 b = *(const ushort4*)&y[((size_t)kz * NSLOT + s2) * HID + c];
    r0 += p1 * bf2f(a.x) + p2 * bf2f(b.x);
    r1 += p1 * bf2f(a.y) + p2 * bf2f(b.y);
    r2 += p1 * bf2f(a.z) + p2 * bf2f(b.z);
    r3 += p1 * bf2f(a.w) + p2 * bf2f(b.w);
  }
  *(f32x4*)&out[(size_t)n * HID + c] = (f32x4){r0, r1, r2, r3};
}

// ---------------- tier-3: atomic-epilogue GEMM2 (round-7 proven, single-buffer) ----------------
__global__ __launch_bounds__(256) void gemm2_fast_atomic(
    const unsigned short* __restrict__ h1, const unsigned short* __restrict__ w2t,
    const int* __restrict__ rowtok, const float* __restrict__ rowprob,
    const int* __restrict__ counts, const int* __restrict__ offs,
    float* __restrict__ out) {
  const int e   = blockIdx.z;
  const int cnt = counts[e];
  const int m0  = blockIdx.y * 128;
  if (m0 >= cnt) return;
  const int n0  = blockIdx.x * 128;
  const int seg = offs[e];

  __shared__ alignas(16) unsigned short Al[128 * 32];
  __shared__ alignas(16) unsigned short Bl[128 * 32];

  const int t  = threadIdx.x;
  const int l  = t & 63;
  const int w  = t >> 6;
  const int wr = w >> 1, wc = w & 1;
  const int lr = l & 15, hi = l >> 4;

  const int rowS = t >> 2;
  const int kc   = (((t & 3) ^ ((t >> 3) & 3)) * 8);
  const int ra0 = m0 + rowS      < cnt ? m0 + rowS      : cnt - 1;
  const int ra1 = m0 + rowS + 64 < cnt ? m0 + rowS + 64 : cnt - 1;
  const unsigned short* aptr0 = h1 + (size_t)(seg + ra0) * FFN + kc;
  const unsigned short* aptr1 = h1 + (size_t)(seg + ra1) * FFN + kc;
  const unsigned short* bptr0 = w2t + ((size_t)e * HID + n0 + rowS)      * FFN + kc;
  const unsigned short* bptr1 = w2t + ((size_t)e * HID + n0 + rowS + 64) * FFN + kc;
  unsigned short* const ldsA0 = Al + (t & 192) * 8;
  unsigned short* const ldsB0 = Bl + (t & 192) * 8;
  const int koff = (hi ^ ((lr >> 1) & 3)) * 8;

  f32x4 acc[4][4];
  #pragma unroll
  for (int i = 0; i < 4; ++i)
    #pragma unroll
    for (int j = 0; j < 4; ++j) acc[i][j] = (f32x4){0.f, 0.f, 0.f, 0.f};

  for (int k0 = 0; k0 < FFN; k0 += 32) {
    gload16(aptr0 + k0, ldsA0);
    gload16(aptr1 + k0, ldsA0 + 2048);
    gload16(bptr0 + k0, ldsB0);
    gload16(bptr1 + k0, ldsB0 + 2048);
    __syncthreads();
    short8 af[4], bfr[4];
    #pragma unroll
    for (int mi = 0; mi < 4; ++mi) af[mi]  = *(const short8*)&Al[(wr * 64 + mi * 16 + lr) * 32 + koff];
    #pragma unroll
    for (int ni = 0; ni < 4; ++ni) bfr[ni] = *(const short8*)&Bl[(wc * 64 + ni * 16 + lr) * 32 + koff];
    #pragma unroll
    for (int mi = 0; mi < 4; ++mi)
      #pragma unroll
      for (int ni = 0; ni < 4; ++ni)
        acc[mi][ni] = __builtin_amdgcn_mfma_f32_16x16x32_bf16(af[mi], bfr[ni], acc[mi][ni], 0, 0, 0);
    __syncthreads();
  }

  #pragma unroll
  for (int mi = 0; mi < 4; ++mi) {
    #pragma unroll
    for (int r = 0; r < 4; ++r) {
      const int grow = m0 + wr * 64 + mi * 16 + hi * 4 + r;
      if (grow < cnt) {
        const int slot = seg + grow;
        const int tok  = rowtok[slot];
        const float p  = rowprob[slot];
        #pragma unroll
        for (int ni = 0; ni < 4; ++ni)
          atomicAdd(&out[(size_t)tok * HID + n0 + wc * 64 + ni * 16 + lr], p * acc[mi][ni][r]);
      }
    }
  }
}

// ================= tier-4 fallback (round-0 proven 64x64 GEMMs) =================
__global__ __launch_bounds__(256) void gemm1_old(
    const float* __restrict__ x, const float* __restrict__ w1,
    const int* __restrict__ rowtok, const int* __restrict__ counts,
    const int* __restrict__ offs, unsigned short* __restrict__ h1) {
  const int e   = blockIdx.z;
  const int cnt = counts[e];
  const int m0  = blockIdx.y * 64;
  if (m0 >= cnt) return;
  const int n0  = blockIdx.x * 64;
  const int seg = offs[e];
  __shared__ unsigned short Al[64 * 40];
  __shared__ unsigned short Bl[64 * 40];
  const int t  = threadIdx.x;
  const int l  = t & 63;
  const int wv = t >> 6;
  const int wr = wv >> 1, wc = wv & 1;
  const int am  = t >> 2;
  const int akb = (t & 3) * 8;
  const int amg = m0 + am;
  const bool aval = (amg < cnt);
  const float* aptr = aval ? (x + (size_t)rowtok[seg + amg] * HID + akb) : x;
  const int bn  = t & 63;
  const int bkg = (t >> 6) * 8;
  const float* bptr = w1 + (size_t)e * FFN + n0 + bn;
  f32x4 acc[2][2];
  #pragma unroll
  for (int i = 0; i < 2; ++i)
    #pragma unroll
    for (int j = 0; j < 2; ++j) acc[i][j] = (f32x4){0.f, 0.f, 0.f, 0.f};
  const int kreg = (l >> 4) * 8;
  const int lr   = l & 15;
  for (int k0 = 0; k0 < HID; k0 += 32) {
    short8 av = (short8){0,0,0,0,0,0,0,0};
    if (aval) {
      const f32x4 v0 = *(const f32x4*)(aptr + k0);
      const f32x4 v1 = *(const f32x4*)(aptr + k0 + 4);
      #pragma unroll
      for (int j = 0; j < 4; ++j) { av[j] = (short)f2bf(v0[j]); av[4 + j] = (short)f2bf(v1[j]); }
    }
    *(short8*)&Al[am * 40 + akb] = av;
    short8 bv;
    #pragma unroll
    for (int j = 0; j < 8; ++j) bv[j] = (short)f2bf(bptr[(size_t)(k0 + bkg + j) * WROW]);
    *(short8*)&Bl[bn * 40 + bkg] = bv;
    __syncthreads();
    short8 af[2], bfr[2];
    #pragma unroll
    for (int mi = 0; mi < 2; ++mi) af[mi]  = *(const short8*)&Al[(wr * 32 + mi * 16 + lr) * 40 + kreg];
    #pragma unroll
    for (int ni = 0; ni < 2; ++ni) bfr[ni] = *(const short8*)&Bl[(wc * 32 + ni * 16 + lr) * 40 + kreg];
    #pragma unroll
    for (int mi = 0; mi < 2; ++mi)
      #pragma unroll
      for (int ni = 0; ni < 2; ++ni)
        acc[mi][ni] = __builtin_amdgcn_mfma_f32_16x16x32_bf16(af[mi], bfr[ni], acc[mi][ni], 0, 0, 0);
    __syncthreads();
  }
  const int kq = l >> 4;
  #pragma unroll
  for (int mi = 0; mi < 2; ++mi) {
    #pragma unroll
    for (int r = 0; r < 4; ++r) {
      const int grow = m0 + wr * 32 + mi * 16 + kq * 4 + r;
      if (grow < cnt) {
        #pragma unroll
        for (int ni = 0; ni < 2; ++ni) {
          const float v = acc[mi][ni][r];
          const float g = 0.5f * v * (1.0f + erff(v * 0.70710678118654752f));
          h1[(size_t)(seg + grow) * FFN + n0 + wc * 32 + ni * 16 + lr] = f2bf(g);
        }
      }
    }
  }
}

__global__ __launch_bounds__(256) void gemm2_old(
    const unsigned short* __restrict__ h1, const float* __restrict__ w2,
    const int* __restrict__ rowtok, const float* __restrict__ rowprob,
    const int* __restrict__ counts, const int* __restrict__ offs,
    float* __restrict__ out) {
  const int e   = blockIdx.z;
  const int cnt = counts[e];
  const int m0  = blockIdx.y * 64;
  if (m0 >= cnt) return;
  const int n0  = blockIdx.x * 64;
  const int seg = offs[e];
  __shared__ unsigned short Al[64 * 40];
  __shared__ unsigned short Bl[64 * 40];
  const int t  = threadIdx.x;
  const int l  = t & 63;
  const int wv = t >> 6;
  const int wr = wv >> 1, wc = wv & 1;
  const int am  = t >> 2;
  const int akb = (t & 3) * 8;
  const int amg = m0 + am;
  const bool aval = (amg < cnt);
  const unsigned short* aptr = aval ? (h1 + (size_t)(seg + amg) * FFN + akb) : h1;
  const int bn  = t & 63;
  const int bkg = (t >> 6) * 8;
  const float* bptr = w2 + (size_t)e * FFN * HID + n0 + bn;
  f32x4 acc[2][2];
  #pragma unroll
  for (int i = 0; i < 2; ++i)
    #pragma unroll
    for (int j = 0; j < 2; ++j) acc[i][j] = (f32x4){0.f, 0.f, 0.f, 0.f};
  const int kreg = (l >> 4) * 8;
  const int lr   = l & 15;
  for (int k0 = 0; k0 < FFN; k0 += 32) {
    short8 av = (short8){0,0,0,0,0,0,0,0};
    if (aval) av = *(const short8*)(aptr + k0);
    *(short8*)&Al[am * 40 + akb] = av;
    short8 bv;
    #pragma unroll
    for (int j = 0; j < 8; ++j) bv[j] = (short)f2bf(bptr[(size_t)(k0 + bkg + j) * HID]);
    *(short8*)&Bl[bn * 40 + bkg] = bv;
    __syncthreads();
    short8 af[2], bfr[2];
    #pragma unroll
    for (int mi = 0; mi < 2; ++mi) af[mi]  = *(const short8*)&Al[(wr * 32 + mi * 16 + lr) * 40 + kreg];
    #pragma unroll
    for (int ni = 0; ni < 2; ++ni) bfr[ni] = *(const short8*)&Bl[(wc * 32 + ni * 16 + lr) * 40 + kreg];
    #pragma unroll
    for (int mi = 0; mi < 2; ++mi)
      #pragma unroll
      for (int ni = 0; ni < 2; ++ni)
        acc[mi][ni] = __builtin_amdgcn_mfma_f32_16x16x32_bf16(af[mi], bfr[ni], acc[mi][ni], 0, 0, 0);
    __syncthreads();
  }
  const int kq = l >> 4;
  #pragma unroll
  for (int mi = 0; mi < 2; ++mi) {
    #pragma unroll
    for (int r = 0; r < 4; ++r) {
      const int grow = m0 + wr * 32 + mi * 16 + kq * 4 + r;
      if (grow < cnt) {
        const int slot = seg + grow;
        const int tok  = rowtok[slot];
        const float p  = rowprob[slot];
        #pragma unroll
        for (int ni = 0; ni < 2; ++ni)
          atomicAdd(&out[(size_t)tok * HID + n0 + wc * 32 + ni * 16 + lr], p * acc[mi][ni][r]);
      }
    }
  }
}

extern "C" void kernel_launch(void* const* d_in, const int* in_sizes, int n_in,
                              void* d_out, int out_size, void* d_ws, size_t ws_size,
                              hipStream_t stream) {
  const float* x  = (const float*)d_in[0];
  const float* rw = (const float*)d_in[1];
  const float* w1 = (const float*)d_in[2];
  const float* w2 = (const float*)d_in[3];
  float* out = (float*)d_out;

  // ws layout
  int*   counts  = (int*)d_ws;                 // 8
  int*   offs    = counts + 8;                 // 8
  int*   tokslot = counts + 16;                // NSLOT
  int*   eidx    = tokslot + NSLOT;            // NSLOT
  float* probs   = (float*)(eidx + NSLOT);     // NSLOT
  int*   rowtok  = (int*)(probs + NSLOT);      // NSLOT
  float* rowprob = (float*)(rowtok + NSLOT);   // NSLOT
  unsigned short* h1  = (unsigned short*)(rowprob + NSLOT);  // 32 MiB
  unsigned short* xb  = h1 + (size_t)NSLOT * FFN;            // 8 MiB
  unsigned short* wt  = xb + (size_t)N_TOK * HID;            // 32 MiB (w1t)
  unsigned short* wt2 = wt + (size_t)WROW * HID;             // seq path: y; merged: w2t
  unsigned short* ymg = wt2 + (size_t)WROW * HID;            // merged path: y

  const size_t need_base   = (size_t)((char*)wt2 - (char*)d_ws);       // ~76 MiB
  const size_t need_seq_y1 = need_base + (size_t)NSLOT * HID * 2;      // +16 MiB
  const size_t need_seq_y2 = need_base + (size_t)2 * NSLOT * HID * 2;  // +32 MiB
  const size_t need_mrg_y1 = need_base + (size_t)WROW * HID * 2 + (size_t)NSLOT * HID * 2;       // +48 MiB
  const size_t need_mrg_y2 = need_base + (size_t)WROW * HID * 2 + (size_t)2 * NSLOT * HID * 2;   // +64 MiB
  const bool fast = (ws_size >= need_base);

  if (fast && ws_size >= need_mrg_y1) {
    // merged router + both tconvs in one launch, then dispatch
    prep_kernel<<<N_TOK / 4 + 8192, 256, 0, stream>>>(x, rw, eidx, probs, xb, w1, w2, wt, wt2);
    dispatch_kernel<<<1, 256, 0, stream>>>(eidx, probs, counts, offs, rowtok, rowprob, tokslot);
    gemm1_fast<<<1152, 256, 0, stream>>>(xb, wt, rowtok, counts, offs, h1);
    if (ws_size >= need_mrg_y2) {
      gemm2_fast<2><<<1152, 256, 0, stream>>>(h1, wt2, counts, offs, ymg);
      combine_kernel<2><<<N_TOK, 256, 0, stream>>>(ymg, tokslot, probs, out);
    } else {
      gemm2_fast<1><<<576, 256, 0, stream>>>(h1, wt2, counts, offs, ymg);
      combine_kernel<1><<<N_TOK, 256, 0, stream>>>(ymg, tokslot, probs, out);
    }
  } else if (fast) {
    // sequential tconv, wt reused
    prep_kernel<<<N_TOK / 4, 256, 0, stream>>>(x, rw, eidx, probs, xb, w1, w2, wt, wt);  // router only
    dispatch_kernel<<<1, 256, 0, stream>>>(eidx, probs, counts, offs, rowtok, rowprob, tokslot);
    tconv_kernel<<<dim3(WROW / 64, HID / 64), 256, 0, stream>>>(w1, wt, HID, WROW, HID);
    gemm1_fast<<<1152, 256, 0, stream>>>(xb, wt, rowtok, counts, offs, h1);
    tconv_kernel<<<dim3(HID / 64, WROW / 64), 256, 0, stream>>>(w2, wt, WROW, HID, FFN);
    if (ws_size >= need_seq_y2) {
      gemm2_fast<2><<<1152, 256, 0, stream>>>(h1, wt, counts, offs, wt2);
      combine_kernel<2><<<N_TOK, 256, 0, stream>>>(wt2, tokslot, probs, out);
    } else if (ws_size >= need_seq_y1) {
      gemm2_fast<1><<<576, 256, 0, stream>>>(h1, wt, counts, offs, wt2);
      combine_kernel<1><<<N_TOK, 256, 0, stream>>>(wt2, tokslot, probs, out);
    } else {
      hipMemsetAsync(d_out, 0, (size_t)out_size * sizeof(float), stream);
      gemm2_fast_atomic<<<dim3(HID / 128, NSLOT / 128, NEXP), 256, 0, stream>>>(h1, wt, rowtok, rowprob, counts, offs, out);
    }
  } else {
    hipMemsetAsync(d_out, 0, (size_t)out_size * sizeof(float), stream);
    prep_kernel<<<N_TOK / 4, 256, 0, stream>>>(x, rw, eidx, probs, nullptr, w1, w2, nullptr, nullptr);
    dispatch_kernel<<<1, 256, 0, stream>>>(eidx, probs, counts, offs, rowtok, rowprob, tokslot);
    gemm1_old<<<dim3(FFN / 64, NSLOT / 64, NEXP), 256, 0, stream>>>(x, w1, rowtok, counts, offs, h1);
    gemm2_old<<<dim3(HID / 64, NSLOT / 64, NEXP), 256, 0, stream>>>(h1, w2, rowtok, rowprob, counts, offs, out);
  }
}

// Round 14
// 201.417 us; speedup vs baseline: 1.1770x; 1.0042x over previous
//
#include <hip/hip_runtime.h>
#include <hip/hip_bf16.h>
#include <math.h>

#define N_TOK 4096
#define HID   1024
#define FFN   2048
#define NEXP  8
#define WROW  (NEXP*FFN)    /* 16384: row stride of w1 */
#define NSLOT (N_TOK*2)     /* 8192 (token,k) slots    */
#define NCHUNK (NSLOT/64)   /* 128 ballot chunks       */

typedef __attribute__((ext_vector_type(4))) float f32x4;
typedef __attribute__((ext_vector_type(8))) short short8;

__device__ inline unsigned short f2bf(float f) {
  union { float f; unsigned u; } v; v.f = f;
  unsigned r = v.u + 0x7fffu + ((v.u >> 16) & 1u);   // RNE to bf16
  return (unsigned short)(r >> 16);
}
__device__ __forceinline__ float bf2f(unsigned short u) {
  union { unsigned u; float f; } v; v.u = ((unsigned)u) << 16; return v.f;
}

// tanh-form GELU: |err| vs exact erf-gelu <= ~3e-3, sub-ulp of bf16 storage of h1.
__device__ __forceinline__ float gelu_f(float v) {
  const float u = 1.5957691216057308f * v + 0.07135481627f * (v * v * v);
  return v / (1.f + __expf(-u));
}

__device__ __forceinline__ void gload16(const void* g, void* l) {
  __builtin_amdgcn_global_load_lds((const __attribute__((address_space(1))) void*)g,
                                   (__attribute__((address_space(3))) void*)l, 16, 0, 0);
}

// Proven config (r13 = 202.3us best): 128^2 tile, BK=32, 3-buffer depth-2
// vmcnt(4), T1 XCD-swizzle, T2 chunk-swizzle (conflicts 4.39M->0), T5 setprio.
// r9: 256^2 tile -> 1 block/CU -> regression. r12: depth-3 (64KB LDS) -> 1
// block/CU -> regression. Cross-block overlap at 2-3 blocks/CU is the win
// condition for this M=8192/K=1-2K grouped shape; GEMM cores are frozen.
// Structural floor model: GEMMs ~135 + prep ~34 (HBM-bound: 217MB) + misc ~30.

// ---------------- prep: router (blocks 0..1023) + both tconvs (blocks 1024..9215) ----------------
__global__ __launch_bounds__(256) void prep_kernel(
    const float* __restrict__ x, const float* __restrict__ rw,
    int* __restrict__ eidx, float* __restrict__ probs, unsigned short* __restrict__ xb,
    const float* __restrict__ w1, const float* __restrict__ w2,
    unsigned short* __restrict__ w1t, unsigned short* __restrict__ w2t) {
  __shared__ float rwT[NEXP][HID];   // 32 KB (router)
  __shared__ float tile[64][65];     // 16.6 KB (tconv)
  const int t = threadIdx.x;

  if (blockIdx.x < N_TOK / 4) {
    // ---- router: 4 tokens/block, rw^T in LDS, no atomics ----
    #pragma unroll
    for (int it = 0; it < 8; ++it) {
      const int flat = t * 4 + it * 1024;
      const f32x4 v = *(const f32x4*)&rw[flat];
      #pragma unroll
      for (int j = 0; j < 4; ++j) rwT[(flat + j) & 7][(flat + j) >> 3] = v[j];
    }
    __syncthreads();

    const int w = t >> 6, l = t & 63;
    const int n = blockIdx.x * 4 + w;
    const float* xr = x + (size_t)n * HID;
    float acc[NEXP];
    #pragma unroll
    for (int e = 0; e < NEXP; ++e) acc[e] = 0.f;

    #pragma unroll
    for (int j = 0; j < 4; ++j) {
      const int i = l * 4 + j * 256;
      const f32x4 xv = *(const f32x4*)&xr[i];
      if (xb) {
        ushort4 o;
        o.x = f2bf(xv[0]); o.y = f2bf(xv[1]); o.z = f2bf(xv[2]); o.w = f2bf(xv[3]);
        *(ushort4*)&xb[(size_t)n * HID + i] = o;
      }
      #pragma unroll
      for (int e = 0; e < NEXP; ++e) {
        const f32x4 wv = *(const f32x4*)&rwT[e][i];
        acc[e] += xv[0] * wv[0] + xv[1] * wv[1] + xv[2] * wv[2] + xv[3] * wv[3];
      }
    }
    #pragma unroll
    for (int e = 0; e < NEXP; ++e) {
      float s = acc[e];
      #pragma unroll
      for (int off = 32; off; off >>= 1) s += __shfl_xor(s, off);
      acc[e] = s;
    }
    if (l == 0) {
      float m = acc[0];
      #pragma unroll
      for (int e = 1; e < NEXP; ++e) m = fmaxf(m, acc[e]);
      float p[NEXP]; float den = 0.f;
      #pragma unroll
      for (int e = 0; e < NEXP; ++e) { p[e] = expf(acc[e] - m); den += p[e]; }
      const float inv = 1.f / den;
      int e1 = 0; float b1 = -1.f;
      #pragma unroll
      for (int e = 0; e < NEXP; ++e) if (p[e] > b1) { b1 = p[e]; e1 = e; }
      int e2 = 0; float b2 = -1.f;
      #pragma unroll
      for (int e = 0; e < NEXP; ++e) if (e != e1 && p[e] > b2) { b2 = p[e]; e2 = e; }
      eidx[n * 2 + 0] = e1; eidx[n * 2 + 1] = e2;
      probs[n * 2 + 0] = b1 * inv; probs[n * 2 + 1] = b2 * inv;
    }
    return;
  }

  // ---- tconv: in [R][C] fp32 -> out bf16 [r/RB][C][r%RB] ----
  int b = blockIdx.x - N_TOK / 4;
  const float* in; unsigned short* out; int C, RB, r0, c0;
  if (b < 4096) {                 // w1 [1024][16384] -> w1t [16384][1024]
    in = w1; out = w1t; C = WROW; RB = HID;
    c0 = (b & 255) * 64; r0 = (b >> 8) * 64;
  } else {                        // w2 [16384][1024] -> w2t [8][1024][2048]
    b -= 4096;
    in = w2; out = w2t; C = HID; RB = FFN;
    c0 = (b & 15) * 64; r0 = (b >> 4) * 64;
  }
  const int tr = t >> 4;
  const int tc4 = (t & 15) * 4;
  #pragma unroll
  for (int i = 0; i < 4; ++i) {
    const int r = tr + i * 16;
    const f32x4 v = *(const f32x4*)&in[(size_t)(r0 + r) * C + c0 + tc4];
    tile[r][tc4 + 0] = v[0]; tile[r][tc4 + 1] = v[1];
    tile[r][tc4 + 2] = v[2]; tile[r][tc4 + 3] = v[3];
  }
  __syncthreads();
  const int eb  = r0 / RB;
  const int rm0 = r0 % RB;
  #pragma unroll
  for (int i = 0; i < 4; ++i) {
    const int c = tr + i * 16;
    ushort4 o;
    o.x = f2bf(tile[tc4 + 0][c]); o.y = f2bf(tile[tc4 + 1][c]);
    o.z = f2bf(tile[tc4 + 2][c]); o.w = f2bf(tile[tc4 + 3][c]);
    const size_t oidx = (size_t)eb * C * RB + (size_t)(c0 + c) * RB + rm0 + tc4;
    *(ushort4*)&out[oidx] = o;
  }
}

// ---------------- dispatch: single block; ballot histogram + scan + rank scatter ----------------
__global__ __launch_bounds__(256) void dispatch_kernel(
    const int* __restrict__ eidx, const float* __restrict__ probs,
    int* __restrict__ counts, int* __restrict__ offs,
    int* __restrict__ rowtok, float* __restrict__ rowprob,
    int* __restrict__ tokslot) {
  __shared__ int chunkbase[NCHUNK][NEXP];
  __shared__ int tot[NEXP], off_s[NEXP];
  const int t = threadIdx.x;
  const int w = t >> 6, l = t & 63;

  for (int c = w; c < NCHUNK; c += 4) {
    const int e = eidx[c * 64 + l];
    #pragma unroll
    for (int xp = 0; xp < NEXP; ++xp) {
      const unsigned long long m = __ballot(e == xp);
      if (l == xp) chunkbase[c][xp] = __popcll(m);
    }
  }
  __syncthreads();

  if (t < NEXP) {
    int a = 0;
    for (int c = 0; c < NCHUNK; ++c) {
      const int v = chunkbase[c][t];
      chunkbase[c][t] = a;
      a += v;
    }
    tot[t] = a;
  }
  __syncthreads();
  if (t == 0) {
    int a = 0;
    for (int e = 0; e < NEXP; ++e) { off_s[e] = a; offs[e] = a; counts[e] = tot[e]; a += tot[e]; }
  }
  __syncthreads();

  for (int c = w; c < NCHUNK; c += 4) {
    const int s = c * 64 + l;
    const int e = eidx[s];
    unsigned long long mask_e = 0;
    #pragma unroll
    for (int xp = 0; xp < NEXP; ++xp) {
      const unsigned long long m = __ballot(e == xp);
      if (e == xp) mask_e = m;
    }
    const unsigned long long below = mask_e & ((1ull << l) - 1ull);
    const int pos = off_s[e] + chunkbase[c][e] + __popcll(below);
    rowtok[pos]  = s >> 1;
    rowprob[pos] = probs[s];
    tokslot[s]   = pos;
  }
}

// ---------------- standalone tconv (seq path) ----------------
__global__ __launch_bounds__(256) void tconv_kernel(
    const float* __restrict__ in, unsigned short* __restrict__ out,
    int R, int C, int RB) {
  __shared__ float tile[64][65];
  const int r0 = blockIdx.y * 64, c0 = blockIdx.x * 64;
  const int t = threadIdx.x;
  const int tr = t >> 4;
  const int tc4 = (t & 15) * 4;
  #pragma unroll
  for (int i = 0; i < 4; ++i) {
    const int r = tr + i * 16;
    const f32x4 v = *(const f32x4*)&in[(size_t)(r0 + r) * C + c0 + tc4];
    tile[r][tc4 + 0] = v[0]; tile[r][tc4 + 1] = v[1];
    tile[r][tc4 + 2] = v[2]; tile[r][tc4 + 3] = v[3];
  }
  __syncthreads();
  const int eb  = r0 / RB;
  const int rm0 = r0 % RB;
  #pragma unroll
  for (int i = 0; i < 4; ++i) {
    const int c = tr + i * 16;
    ushort4 o;
    o.x = f2bf(tile[tc4 + 0][c]); o.y = f2bf(tile[tc4 + 1][c]);
    o.z = f2bf(tile[tc4 + 2][c]); o.w = f2bf(tile[tc4 + 3][c]);
    const size_t oidx = (size_t)eb * C * RB + (size_t)(c0 + c) * RB + rm0 + tc4;
    *(ushort4*)&out[oidx] = o;
  }
}

// ------- grouped GEMM1: 128x128, BK=32, 3-buffer depth-2 counted-vmcnt, T2+T1+T5, m-loop -------
__global__ __launch_bounds__(256) void gemm1_fast(
    const unsigned short* __restrict__ xb, const unsigned short* __restrict__ w1t,
    const int* __restrict__ rowtok, const int* __restrict__ counts,
    const int* __restrict__ offs, unsigned short* __restrict__ h1) {
  // T1 bijective XCD swizzle (G=1024, %8==0); decode 16 nx x 8 my x 8 e
  int wg = blockIdx.x;
  wg = (wg & 7) * (1024 / 8) + (wg >> 3);
  const int bx = wg & 15;
  const int by = (wg >> 4) & 7;
  const int e  = wg >> 7;

  const int cnt = counts[e];
  const int n0  = bx * 128;
  const int seg = offs[e];

  __shared__ alignas(16) unsigned short Al[3][128 * 32];
  __shared__ alignas(16) unsigned short Bl[3][128 * 32];

  const int t  = threadIdx.x;
  const int l  = t & 63;
  const int w  = t >> 6;
  const int wr = w >> 1, wc = w & 1;
  const int lr = l & 15, hi = l >> 4;

  const int rowS = t >> 2;
  const int kc   = (((t & 3) ^ ((t >> 3) & 3)) * 8);    // T2 pre-swizzled global chunk
  const unsigned short* bptr0 = w1t + ((size_t)e * FFN + n0 + rowS) * HID + kc;
  const unsigned short* bptr1 = bptr0 + (size_t)64 * HID;
  const int ldst = (t & 192) * 8;
  const int koff = (hi ^ ((lr >> 1) & 3)) * 8;          // T2 swizzled read chunk
  const int NT = HID / 32;                              // 32 K-tiles

  bool firstm = true;
  for (int m0 = by * 128; m0 < cnt; m0 += 8 * 128) {
    if (!firstm) __syncthreads();                       // LDS reuse fence between m-iters
    firstm = false;

    const int ra0 = m0 + rowS      < cnt ? m0 + rowS      : cnt - 1;
    const int ra1 = m0 + rowS + 64 < cnt ? m0 + rowS + 64 : cnt - 1;
    const unsigned short* aptr0 = xb + (size_t)rowtok[seg + ra0] * HID + kc;
    const unsigned short* aptr1 = xb + (size_t)rowtok[seg + ra1] * HID + kc;

    f32x4 acc[4][4];
    #pragma unroll
    for (int i = 0; i < 4; ++i)
      #pragma unroll
      for (int j = 0; j < 4; ++j) acc[i][j] = (f32x4){0.f, 0.f, 0.f, 0.f};

    auto STAGE = [&](int b, int k0) {                   // exactly 4 uniform vmem ops/thread
      gload16(aptr0 + k0, &Al[b][ldst]);
      gload16(aptr1 + k0, &Al[b][ldst + 2048]);
      gload16(bptr0 + k0, &Bl[b][ldst]);
      gload16(bptr1 + k0, &Bl[b][ldst + 2048]);
    };
    auto COMPUTE = [&](int b) {
      short8 af[4], bfr[4];
      #pragma unroll
      for (int mi = 0; mi < 4; ++mi) af[mi]  = *(const short8*)&Al[b][(wr * 64 + mi * 16 + lr) * 32 + koff];
      #pragma unroll
      for (int ni = 0; ni < 4; ++ni) bfr[ni] = *(const short8*)&Bl[b][(wc * 64 + ni * 16 + lr) * 32 + koff];
      __builtin_amdgcn_s_setprio(1);                    // T5
      #pragma unroll
      for (int mi = 0; mi < 4; ++mi)
        #pragma unroll
        for (int ni = 0; ni < 4; ++ni)
          acc[mi][ni] = __builtin_amdgcn_mfma_f32_16x16x32_bf16(af[mi], bfr[ni], acc[mi][ni], 0, 0, 0);
      __builtin_amdgcn_s_setprio(0);
    };

    STAGE(0, 0);
    STAGE(1, 32);
    asm volatile("s_waitcnt vmcnt(4)" ::: "memory");    // tile0 landed; tile1 in flight
    __builtin_amdgcn_s_barrier();
    __builtin_amdgcn_sched_barrier(0);
    int cur = 0;
    for (int tt = 0; tt < NT; ++tt) {
      if (tt + 2 < NT) {
        int b2 = cur + 2; if (b2 >= 3) b2 -= 3;
        STAGE(b2, (tt + 2) * 32);
      }
      COMPUTE(cur);
      if (tt + 1 < NT) {
        if (tt + 2 < NT) asm volatile("s_waitcnt vmcnt(4)" ::: "memory");
        else             asm volatile("s_waitcnt vmcnt(0)" ::: "memory");
        __builtin_amdgcn_s_barrier();
        __builtin_amdgcn_sched_barrier(0);
      }
      ++cur; if (cur == 3) cur = 0;
    }

    #pragma unroll
    for (int mi = 0; mi < 4; ++mi) {
      #pragma unroll
      for (int r = 0; r < 4; ++r) {
        const int grow = m0 + wr * 64 + mi * 16 + hi * 4 + r;
        if (grow < cnt) {
          const size_t rowoff = (size_t)(seg + grow) * FFN + n0 + wc * 64 + lr;
          #pragma unroll
          for (int ni = 0; ni < 4; ++ni)
            h1[rowoff + ni * 16] = f2bf(gelu_f(acc[mi][ni][r]));
        }
      }
    }
  }
}

// ------- grouped GEMM2: 128x128, BK=32, 3-buffer depth-2 counted-vmcnt, T2+T1+T5, m-loop -------
template<int KS>
__global__ __launch_bounds__(256) void gemm2_fast(
    const unsigned short* __restrict__ h1, const unsigned short* __restrict__ w2t,
    const int* __restrict__ counts, const int* __restrict__ offs,
    unsigned short* __restrict__ y) {
  constexpr int G = 512 * KS;                           // 8 nx x 8 my x 8 e x KS; %8==0
  int wg = blockIdx.x;
  wg = (wg & 7) * (G / 8) + (wg >> 3);
  const int bx = wg & 7;
  const int by = (wg >> 3) & 7;
  const int e  = (wg >> 6) & 7;
  const int kz = wg >> 9;

  const int cnt = counts[e];
  const int n0  = bx * 128;
  const int seg = offs[e];
  constexpr int KLEN = FFN / KS;
  const int kbase = kz * KLEN;

  __shared__ alignas(16) unsigned short Al[3][128 * 32];
  __shared__ alignas(16) unsigned short Bl[3][128 * 32];

  const int t  = threadIdx.x;
  const int l  = t & 63;
  const int w  = t >> 6;
  const int wr = w >> 1, wc = w & 1;
  const int lr = l & 15, hi = l >> 4;

  const int rowS = t >> 2;
  const int kc   = (((t & 3) ^ ((t >> 3) & 3)) * 8);
  const unsigned short* bptr0 = w2t + ((size_t)e * HID + n0 + rowS) * FFN + kbase + kc;
  const unsigned short* bptr1 = bptr0 + (size_t)64 * FFN;
  const int ldst = (t & 192) * 8;
  const int koff = (hi ^ ((lr >> 1) & 3)) * 8;
  const int NT = KLEN / 32;

  bool firstm = true;
  for (int m0 = by * 128; m0 < cnt; m0 += 8 * 128) {
    if (!firstm) __syncthreads();
    firstm = false;

    const int ra0 = m0 + rowS      < cnt ? m0 + rowS      : cnt - 1;
    const int ra1 = m0 + rowS + 64 < cnt ? m0 + rowS + 64 : cnt - 1;
    const unsigned short* aptr0 = h1 + (size_t)(seg + ra0) * FFN + kbase + kc;
    const unsigned short* aptr1 = h1 + (size_t)(seg + ra1) * FFN + kbase + kc;

    f32x4 acc[4][4];
    #pragma unroll
    for (int i = 0; i < 4; ++i)
      #pragma unroll
      for (int j = 0; j < 4; ++j) acc[i][j] = (f32x4){0.f, 0.f, 0.f, 0.f};

    auto STAGE = [&](int b, int k0) {
      gload16(aptr0 + k0, &Al[b][ldst]);
      gload16(aptr1 + k0, &Al[b][ldst + 2048]);
      gload16(bptr0 + k0, &Bl[b][ldst]);
      gload16(bptr1 + k0, &Bl[b][ldst + 2048]);
    };
    auto COMPUTE = [&](int b) {
      short8 af[4], bfr[4];
      #pragma unroll
      for (int mi = 0; mi < 4; ++mi) af[mi]  = *(const short8*)&Al[b][(wr * 64 + mi * 16 + lr) * 32 + koff];
      #pragma unroll
      for (int ni = 0; ni < 4; ++ni) bfr[ni] = *(const short8*)&Bl[b][(wc * 64 + ni * 16 + lr) * 32 + koff];
      __builtin_amdgcn_s_setprio(1);                    // T5
      #pragma unroll
      for (int mi = 0; mi < 4; ++mi)
        #pragma unroll
        for (int ni = 0; ni < 4; ++ni)
          acc[mi][ni] = __builtin_amdgcn_mfma_f32_16x16x32_bf16(af[mi], bfr[ni], acc[mi][ni], 0, 0, 0);
      __builtin_amdgcn_s_setprio(0);
    };

    STAGE(0, 0);
    STAGE(1, 32);
    asm volatile("s_waitcnt vmcnt(4)" ::: "memory");
    __builtin_amdgcn_s_barrier();
    __builtin_amdgcn_sched_barrier(0);
    int cur = 0;
    for (int tt = 0; tt < NT; ++tt) {
      if (tt + 2 < NT) {
        int b2 = cur + 2; if (b2 >= 3) b2 -= 3;
        STAGE(b2, (tt + 2) * 32);
      }
      COMPUTE(cur);
      if (tt + 1 < NT) {
        if (tt + 2 < NT) asm volatile("s_waitcnt vmcnt(4)" ::: "memory");
        else             asm volatile("s_waitcnt vmcnt(0)" ::: "memory");
        __builtin_amdgcn_s_barrier();
        __builtin_amdgcn_sched_barrier(0);
      }
      ++cur; if (cur == 3) cur = 0;
    }

    #pragma unroll
    for (int mi = 0; mi < 4; ++mi) {
      #pragma unroll
      for (int r = 0; r < 4; ++r) {
        const int grow = m0 + wr * 64 + mi * 16 + hi * 4 + r;
        if (grow < cnt) {
          const int slot = seg + grow;
          unsigned short* yrow = y + ((size_t)kz * NSLOT + slot) * HID + n0 + wc * 64 + lr;
          #pragma unroll
          for (int ni = 0; ni < 4; ++ni)
            yrow[ni * 16] = f2bf(acc[mi][ni][r]);
        }
      }
    }
  }
}

// ---------------- combine: 2 tokens/block, ushort8 loads ----------------
template<int KS>
__global__ __launch_bounds__(256) void combine_kernel(
    const unsigned short* __restrict__ y, const int* __restrict__ tokslot,
    const float* __restrict__ probs, float* __restrict__ out) {
  const int n = blockIdx.x * 2 + (threadIdx.x >> 7);
  const int c = (threadIdx.x & 127) * 8;
  const int s1 = tokslot[n * 2 + 0], s2 = tokslot[n * 2 + 1];
  const float p1 = probs[n * 2 + 0], p2 = probs[n * 2 + 1];
  float r[8];
  #pragma unroll
  for (int j = 0; j < 8; ++j) r[j] = 0.f;
  #pragma unroll
  for (int kz = 0; kz < KS; ++kz) {
    const short8 a = *(const short8*)&y[((size_t)kz * NSLOT + s1) * HID + c];
    const short8 b = *(const short8*)&y[((size_t)kz * NSLOT + s2) * HID + c];
    #pragma unroll
    for (int j = 0; j < 8; ++j)
      r[j] += p1 * bf2f((unsigned short)a[j]) + p2 * bf2f((unsigned short)b[j]);
  }
  *(f32x4*)&out[(size_t)n * HID + c]     = (f32x4){r[0], r[1], r[2], r[3]};
  *(f32x4*)&out[(size_t)n * HID + c + 4] = (f32x4){r[4], r[5], r[6], r[7]};
}

// ---------------- tier-3: atomic-epilogue GEMM2 (round-7 proven, single-buffer) ----------------
__global__ __launch_bounds__(256) void gemm2_fast_atomic(
    const unsigned short* __restrict__ h1, const unsigned short* __restrict__ w2t,
    const int* __restrict__ rowtok, const float* __restrict__ rowprob,
    const int* __restrict__ counts, const int* __restrict__ offs,
    float* __restrict__ out) {
  const int e   = blockIdx.z;
  const int cnt = counts[e];
  const int m0  = blockIdx.y * 128;
  if (m0 >= cnt) return;
  const int n0  = blockIdx.x * 128;
  const int seg = offs[e];

  __shared__ alignas(16) unsigned short Al[128 * 32];
  __shared__ alignas(16) unsigned short Bl[128 * 32];

  const int t  = threadIdx.x;
  const int l  = t & 63;
  const int w  = t >> 6;
  const int wr = w >> 1, wc = w & 1;
  const int lr = l & 15, hi = l >> 4;

  const int rowS = t >> 2;
  const int kc   = (((t & 3) ^ ((t >> 3) & 3)) * 8);
  const int ra0 = m0 + rowS      < cnt ? m0 + rowS      : cnt - 1;
  const int ra1 = m0 + rowS + 64 < cnt ? m0 + rowS + 64 : cnt - 1;
  const unsigned short* aptr0 = h1 + (size_t)(seg + ra0) * FFN + kc;
  const unsigned short* aptr1 = h1 + (size_t)(seg + ra1) * FFN + kc;
  const unsigned short* bptr0 = w2t + ((size_t)e * HID + n0 + rowS)      * FFN + kc;
  const unsigned short* bptr1 = w2t + ((size_t)e * HID + n0 + rowS + 64) * FFN + kc;
  unsigned short* const ldsA0 = Al + (t & 192) * 8;
  unsigned short* const ldsB0 = Bl + (t & 192) * 8;
  const int koff = (hi ^ ((lr >> 1) & 3)) * 8;

  f32x4 acc[4][4];
  #pragma unroll
  for (int i = 0; i < 4; ++i)
    #pragma unroll
    for (int j = 0; j < 4; ++j) acc[i][j] = (f32x4){0.f, 0.f, 0.f, 0.f};

  for (int k0 = 0; k0 < FFN; k0 += 32) {
    gload16(aptr0 + k0, ldsA0);
    gload16(aptr1 + k0, ldsA0 + 2048);
    gload16(bptr0 + k0, ldsB0);
    gload16(bptr1 + k0, ldsB0 + 2048);
    __syncthreads();
    short8 af[4], bfr[4];
    #pragma unroll
    for (int mi = 0; mi < 4; ++mi) af[mi]  = *(const short8*)&Al[(wr * 64 + mi * 16 + lr) * 32 + koff];
    #pragma unroll
    for (int ni = 0; ni < 4; ++ni) bfr[ni] = *(const short8*)&Bl[(wc * 64 + ni * 16 + lr) * 32 + koff];
    #pragma unroll
    for (int mi = 0; mi < 4; ++mi)
      #pragma unroll
      for (int ni = 0; ni < 4; ++ni)
        acc[mi][ni] = __builtin_amdgcn_mfma_f32_16x16x32_bf16(af[mi], bfr[ni], acc[mi][ni], 0, 0, 0);
    __syncthreads();
  }

  #pragma unroll
  for (int mi = 0; mi < 4; ++mi) {
    #pragma unroll
    for (int r = 0; r < 4; ++r) {
      const int grow = m0 + wr * 64 + mi * 16 + hi * 4 + r;
      if (grow < cnt) {
        const int slot = seg + grow;
        const int tok  = rowtok[slot];
        const float p  = rowprob[slot];
        #pragma unroll
        for (int ni = 0; ni < 4; ++ni)
          atomicAdd(&out[(size_t)tok * HID + n0 + wc * 64 + ni * 16 + lr], p * acc[mi][ni][r]);
      }
    }
  }
}

// ================= tier-4 fallback (round-0 proven 64x64 GEMMs) =================
__global__ __launch_bounds__(256) void gemm1_old(
    const float* __restrict__ x, const float* __restrict__ w1,
    const int* __restrict__ rowtok, const int* __restrict__ counts,
    const int* __restrict__ offs, unsigned short* __restrict__ h1) {
  const int e   = blockIdx.z;
  const int cnt = counts[e];
  const int m0  = blockIdx.y * 64;
  if (m0 >= cnt) return;
  const int n0  = blockIdx.x * 64;
  const int seg = offs[e];
  __shared__ unsigned short Al[64 * 40];
  __shared__ unsigned short Bl[64 * 40];
  const int t  = threadIdx.x;
  const int l  = t & 63;
  const int wv = t >> 6;
  const int wr = wv >> 1, wc = wv & 1;
  const int am  = t >> 2;
  const int akb = (t & 3) * 8;
  const int amg = m0 + am;
  const bool aval = (amg < cnt);
  const float* aptr = aval ? (x + (size_t)rowtok[seg + amg] * HID + akb) : x;
  const int bn  = t & 63;
  const int bkg = (t >> 6) * 8;
  const float* bptr = w1 + (size_t)e * FFN + n0 + bn;
  f32x4 acc[2][2];
  #pragma unroll
  for (int i = 0; i < 2; ++i)
    #pragma unroll
    for (int j = 0; j < 2; ++j) acc[i][j] = (f32x4){0.f, 0.f, 0.f, 0.f};
  const int kreg = (l >> 4) * 8;
  const int lr   = l & 15;
  for (int k0 = 0; k0 < HID; k0 += 32) {
    short8 av = (short8){0,0,0,0,0,0,0,0};
    if (aval) {
      const f32x4 v0 = *(const f32x4*)(aptr + k0);
      const f32x4 v1 = *(const f32x4*)(aptr + k0 + 4);
      #pragma unroll
      for (int j = 0; j < 4; ++j) { av[j] = (short)f2bf(v0[j]); av[4 + j] = (short)f2bf(v1[j]); }
    }
    *(short8*)&Al[am * 40 + akb] = av;
    short8 bv;
    #pragma unroll
    for (int j = 0; j < 8; ++j) bv[j] = (short)f2bf(bptr[(size_t)(k0 + bkg + j) * WROW]);
    *(short8*)&Bl[bn * 40 + bkg] = bv;
    __syncthreads();
    short8 af[2], bfr[2];
    #pragma unroll
    for (int mi = 0; mi < 2; ++mi) af[mi]  = *(const short8*)&Al[(wr * 32 + mi * 16 + lr) * 40 + kreg];
    #pragma unroll
    for (int ni = 0; ni < 2; ++ni) bfr[ni] = *(const short8*)&Bl[(wc * 32 + ni * 16 + lr) * 40 + kreg];
    #pragma unroll
    for (int mi = 0; mi < 2; ++mi)
      #pragma unroll
      for (int ni = 0; ni < 2; ++ni)
        acc[mi][ni] = __builtin_amdgcn_mfma_f32_16x16x32_bf16(af[mi], bfr[ni], acc[mi][ni], 0, 0, 0);
    __syncthreads();
  }
  const int kq = l >> 4;
  #pragma unroll
  for (int mi = 0; mi < 2; ++mi) {
    #pragma unroll
    for (int r = 0; r < 4; ++r) {
      const int grow = m0 + wr * 32 + mi * 16 + kq * 4 + r;
      if (grow < cnt) {
        #pragma unroll
        for (int ni = 0; ni < 2; ++ni) {
          const float v = acc[mi][ni][r];
          const float g = 0.5f * v * (1.0f + erff(v * 0.70710678118654752f));
          h1[(size_t)(seg + grow) * FFN + n0 + wc * 32 + ni * 16 + lr] = f2bf(g);
        }
      }
    }
  }
}

__global__ __launch_bounds__(256) void gemm2_old(
    const unsigned short* __restrict__ h1, const float* __restrict__ w2,
    const int* __restrict__ rowtok, const float* __restrict__ rowprob,
    const int* __restrict__ counts, const int* __restrict__ offs,
    float* __restrict__ out) {
  const int e   = blockIdx.z;
  const int cnt = counts[e];
  const int m0  = blockIdx.y * 64;
  if (m0 >= cnt) return;
  const int n0  = blockIdx.x * 64;
  const int seg = offs[e];
  __shared__ unsigned short Al[64 * 40];
  __shared__ unsigned short Bl[64 * 40];
  const int t  = threadIdx.x;
  const int l  = t & 63;
  const int wv = t >> 6;
  const int wr = wv >> 1, wc = wv & 1;
  const int am  = t >> 2;
  const int akb = (t & 3) * 8;
  const int amg = m0 + am;
  const bool aval = (amg < cnt);
  const unsigned short* aptr = aval ? (h1 + (size_t)(seg + amg) * FFN + akb) : h1;
  const int bn  = t & 63;
  const int bkg = (t >> 6) * 8;
  const float* bptr = w2 + (size_t)e * FFN * HID + n0 + bn;
  f32x4 acc[2][2];
  #pragma unroll
  for (int i = 0; i < 2; ++i)
    #pragma unroll
    for (int j = 0; j < 2; ++j) acc[i][j] = (f32x4){0.f, 0.f, 0.f, 0.f};
  const int kreg = (l >> 4) * 8;
  const int lr   = l & 15;
  for (int k0 = 0; k0 < FFN; k0 += 32) {
    short8 av = (short8){0,0,0,0,0,0,0,0};
    if (aval) av = *(const short8*)(aptr + k0);
    *(short8*)&Al[am * 40 + akb] = av;
    short8 bv;
    #pragma unroll
    for (int j = 0; j < 8; ++j) bv[j] = (short)f2bf(bptr[(size_t)(k0 + bkg + j) * HID]);
    *(short8*)&Bl[bn * 40 + bkg] = bv;
    __syncthreads();
    short8 af[2], bfr[2];
    #pragma unroll
    for (int mi = 0; mi < 2; ++mi) af[mi]  = *(const short8*)&Al[(wr * 32 + mi * 16 + lr) * 40 + kreg];
    #pragma unroll
    for (int ni = 0; ni < 2; ++ni) bfr[ni] = *(const short8*)&Bl[(wc * 32 + ni * 16 + lr) * 40 + kreg];
    #pragma unroll
    for (int mi = 0; mi < 2; ++mi)
      #pragma unroll
      for (int ni = 0; ni < 2; ++ni)
        acc[mi][ni] = __builtin_amdgcn_mfma_f32_16x16x32_bf16(af[mi], bfr[ni], acc[mi][ni], 0, 0, 0);
    __syncthreads();
  }
  const int kq = l >> 4;
  #pragma unroll
  for (int mi = 0; mi < 2; ++mi) {
    #pragma unroll
    for (int r = 0; r < 4; ++r) {
      const int grow = m0 + wr * 32 + mi * 16 + kq * 4 + r;
      if (grow < cnt) {
        const int slot = seg + grow;
        const int tok  = rowtok[slot];
        const float p  = rowprob[slot];
        #pragma unroll
        for (int ni = 0; ni < 2; ++ni)
          atomicAdd(&out[(size_t)tok * HID + n0 + wc * 32 + ni * 16 + lr], p * acc[mi][ni][r]);
      }
    }
  }
}

extern "C" void kernel_launch(void* const* d_in, const int* in_sizes, int n_in,
                              void* d_out, int out_size, void* d_ws, size_t ws_size,
                              hipStream_t stream) {
  const float* x  = (const float*)d_in[0];
  const float* rw = (const float*)d_in[1];
  const float* w1 = (const float*)d_in[2];
  const float* w2 = (const float*)d_in[3];
  float* out = (float*)d_out;

  // ws layout
  int*   counts  = (int*)d_ws;                 // 8
  int*   offs    = counts + 8;                 // 8
  int*   tokslot = counts + 16;                // NSLOT
  int*   eidx    = tokslot + NSLOT;            // NSLOT
  float* probs   = (float*)(eidx + NSLOT);     // NSLOT
  int*   rowtok  = (int*)(probs + NSLOT);      // NSLOT
  float* rowprob = (float*)(rowtok + NSLOT);   // NSLOT
  unsigned short* h1  = (unsigned short*)(rowprob + NSLOT);  // 32 MiB
  unsigned short* xb  = h1 + (size_t)NSLOT * FFN;            // 8 MiB
  unsigned short* wt  = xb + (size_t)N_TOK * HID;            // 32 MiB (w1t)
  unsigned short* wt2 = wt + (size_t)WROW * HID;             // seq path: y; merged: w2t
  unsigned short* ymg = wt2 + (size_t)WROW * HID;            // merged path: y

  const size_t need_base   = (size_t)((char*)wt2 - (char*)d_ws);       // ~76 MiB
  const size_t need_seq_y1 = need_base + (size_t)NSLOT * HID * 2;      // +16 MiB
  const size_t need_seq_y2 = need_base + (size_t)2 * NSLOT * HID * 2;  // +32 MiB
  const size_t need_mrg_y1 = need_base + (size_t)WROW * HID * 2 + (size_t)NSLOT * HID * 2;       // +48 MiB
  const size_t need_mrg_y2 = need_base + (size_t)WROW * HID * 2 + (size_t)2 * NSLOT * HID * 2;   // +64 MiB
  const bool fast = (ws_size >= need_base);

  if (fast && ws_size >= need_mrg_y1) {
    // merged router + both tconvs in one launch, then dispatch
    prep_kernel<<<N_TOK / 4 + 8192, 256, 0, stream>>>(x, rw, eidx, probs, xb, w1, w2, wt, wt2);
    dispatch_kernel<<<1, 256, 0, stream>>>(eidx, probs, counts, offs, rowtok, rowprob, tokslot);
    gemm1_fast<<<1024, 256, 0, stream>>>(xb, wt, rowtok, counts, offs, h1);
    if (ws_size >= need_mrg_y2) {
      gemm2_fast<2><<<1024, 256, 0, stream>>>(h1, wt2, counts, offs, ymg);
      combine_kernel<2><<<N_TOK / 2, 256, 0, stream>>>(ymg, tokslot, probs, out);
    } else {
      gemm2_fast<1><<<512, 256, 0, stream>>>(h1, wt2, counts, offs, ymg);
      combine_kernel<1><<<N_TOK / 2, 256, 0, stream>>>(ymg, tokslot, probs, out);
    }
  } else if (fast) {
    // sequential tconv, wt reused
    prep_kernel<<<N_TOK / 4, 256, 0, stream>>>(x, rw, eidx, probs, xb, w1, w2, wt, wt);  // router only
    dispatch_kernel<<<1, 256, 0, stream>>>(eidx, probs, counts, offs, rowtok, rowprob, tokslot);
    tconv_kernel<<<dim3(WROW / 64, HID / 64), 256, 0, stream>>>(w1, wt, HID, WROW, HID);
    gemm1_fast<<<1024, 256, 0, stream>>>(xb, wt, rowtok, counts, offs, h1);
    tconv_kernel<<<dim3(HID / 64, WROW / 64), 256, 0, stream>>>(w2, wt, WROW, HID, FFN);
    if (ws_size >= need_seq_y2) {
      gemm2_fast<2><<<1024, 256, 0, stream>>>(h1, wt, counts, offs, wt2);
      combine_kernel<2><<<N_TOK / 2, 256, 0, stream>>>(wt2, tokslot, probs, out);
    } else if (ws_size >= need_seq_y1) {
      gemm2_fast<1><<<512, 256, 0, stream>>>(h1, wt, counts, offs, wt2);
      combine_kernel<1><<<N_TOK / 2, 256, 0, stream>>>(wt2, tokslot, probs, out);
    } else {
      hipMemsetAsync(d_out, 0, (size_t)out_size * sizeof(float), stream);
      gemm2_fast_atomic<<<dim3(HID / 128, NSLOT / 128, NEXP), 256, 0, stream>>>(h1, wt, rowtok, rowprob, counts, offs, out);
    }
  } else {
    hipMemsetAsync(d_out, 0, (size_t)out_size * sizeof(float), stream);
    prep_kernel<<<N_TOK / 4, 256, 0, stream>>>(x, rw, eidx, probs, nullptr, w1, w2, nullptr, nullptr);
    dispatch_kernel<<<1, 256, 0, stream>>>(eidx, probs, counts, offs, rowtok, rowprob, tokslot);
    gemm1_old<<<dim3(FFN / 64, NSLOT / 64, NEXP), 256, 0, stream>>>(x, w1, rowtok, counts, offs, h1);
    gemm2_old<<<dim3(HID / 64, NSLOT / 64, NEXP), 256, 0, stream>>>(h1, w2, rowtok, rowprob, counts, offs, out);
  }
}